// Round 2
// baseline (249.143 us; speedup 1.0000x reference)
//
#include <hip/hip_runtime.h>
#include <hip/hip_bf16.h>

#define NB    128
#define CENC  2048
#define FIN   512
#define FHID  8
#define S2D   49
#define SO3D  455
#define HW    49

typedef unsigned short ushort_t;
typedef __bf16 bf16x8 __attribute__((ext_vector_type(8)));
typedef float  f32x4  __attribute__((ext_vector_type(4)));

// async global->LDS, 16B per lane; LDS dest = wave-uniform base + lane*16
#define GLD16(gp, lp) __builtin_amdgcn_global_load_lds( \
    (__attribute__((address_space(1))) const unsigned int*)(gp), \
    (__attribute__((address_space(3))) unsigned int*)(lp), 16, 0, 0)

__device__ __forceinline__ int soff(int l) { return l*(4*l*l-1)/3; }  // sum_{l'<l}(2l'+1)^2

__device__ __forceinline__ ushort_t f2bf(float x) {
  __hip_bfloat16 h = __float2bfloat16(x);
  return *reinterpret_cast<ushort_t*>(&h);
}
__device__ __forceinline__ float bf2f(ushort_t u) {
  __hip_bfloat16 h = *reinterpret_cast<__hip_bfloat16*>(&u);
  return __bfloat162float(h);
}

// ================= device building blocks =================

__device__ __forceinline__ void dev_gemm_nn(float* smem,
    const float* __restrict__ A, const float* __restrict__ B, float* __restrict__ C,
    int M, int N, int K, int lda, int ldb, int ldc, float alpha, int bx, int by)
{
  float* As = smem;
  float* Bs = smem + 32*68;
  const int tid = threadIdx.x;
  const int tx = tid & 15, ty = tid >> 4;
  const int n0 = bx * 64, m0 = by * 64;
  float acc[4][4] = {};
  for (int k0 = 0; k0 < K; k0 += 32) {
    {
      const int kk = tid & 31, mmB = tid >> 5;
      #pragma unroll
      for (int j = 0; j < 8; ++j) {
        const int mm = mmB + 8*j;
        const int m = m0 + mm, k = k0 + kk;
        As[kk*68 + mm] = (m < M && k < K) ? A[(size_t)m*lda + k] : 0.f;
      }
    }
    {
      const int nn = tid & 63, kkB = tid >> 6;
      #pragma unroll
      for (int j = 0; j < 8; ++j) {
        const int kk = kkB + 4*j;
        const int n = n0 + nn, k = k0 + kk;
        Bs[kk*68 + nn] = (n < N && k < K) ? B[(size_t)k*ldb + n] : 0.f;
      }
    }
    __syncthreads();
    #pragma unroll
    for (int kk = 0; kk < 32; ++kk) {
      const float4 a4 = *(const float4*)&As[kk*68 + ty*4];
      const float4 b4 = *(const float4*)&Bs[kk*68 + tx*4];
      const float av[4] = {a4.x,a4.y,a4.z,a4.w};
      const float bv[4] = {b4.x,b4.y,b4.z,b4.w};
      #pragma unroll
      for (int i = 0; i < 4; ++i)
        #pragma unroll
        for (int j = 0; j < 4; ++j)
          acc[i][j] = fmaf(av[i], bv[j], acc[i][j]);
    }
    __syncthreads();
  }
  #pragma unroll
  for (int i = 0; i < 4; ++i) {
    const int m = m0 + ty*4 + i;
    if (m >= M) continue;
    #pragma unroll
    for (int j = 0; j < 4; ++j) {
      const int n = n0 + tx*4 + j;
      if (n >= N) continue;
      C[(size_t)m*ldc + n] = acc[i][j] * alpha;
    }
  }
}

// 64x64 transpose + fp32->bf16 cvt, packed 8B stores.
// out[c*Rp + r] = bf16(in[r*C + c]), zero-padded to (Cp, Rp).
__device__ __forceinline__ void dev_transpose_cvt64(float* smem,
    const float* __restrict__ in, int R, int C,
    ushort_t* __restrict__ out, int Rp, int Cp, int bx, int by)
{
  float (*t)[65] = (float(*)[65])smem;         // 64x65 fp32
  const int c0 = bx*64, r0 = by*64;
  const int tid = threadIdx.x;
  const int cl = tid & 63, rlB = tid >> 6;
  #pragma unroll
  for (int p = 0; p < 16; ++p) {
    const int rl = rlB + p*4;
    const int r = r0 + rl, c = c0 + cl;
    t[rl][cl] = (r < R && c < C) ? in[(size_t)r*C + c] : 0.f;
  }
  __syncthreads();
  // store: each thread packs 4 consecutive r into one uint2 (4x bf16, 8 B)
  #pragma unroll
  for (int p = 0; p < 4; ++p) {
    const int c = p*16 + (tid >> 4);
    const int r4 = (tid & 15) * 4;
    unsigned int lo = (unsigned int)f2bf(t[r4+0][c]) | ((unsigned int)f2bf(t[r4+1][c]) << 16);
    unsigned int hi = (unsigned int)f2bf(t[r4+2][c]) | ((unsigned int)f2bf(t[r4+3][c]) << 16);
    *(uint2*)&out[(size_t)(c0 + c)*Rp + r0 + r4] = make_uint2(lo, hi);
  }
}

__device__ __forceinline__ void dev_sumP(float* smem,
    const float* __restrict__ proj_w, const float* __restrict__ proj_Y,
    float* __restrict__ sumP)
{
  float* colsum = smem;   // 192 floats
  const int tid = threadIdx.x;
  if (tid < 192) {
    float s = 0.f;
    for (int h = 0; h < 49; ++h) s += proj_w[h*192 + tid];
    colsum[tid] = s;
  }
  __syncthreads();
  if (tid < 64) {
    float s = 0.f;
    if (tid < 49) for (int k = 0; k < 192; ++k) s += colsum[k] * proj_Y[k*49 + tid];
    sumP[tid] = (tid < 49) ? s * 0.07216878364870323f : 0.f;
  }
}

// ================= split prep kernels (was one mega-kernel) =================

// A) small fp32 GEMMs + sumP : 74 blocks, 17.4 KB LDS
__global__ __launch_bounds__(256) void prep_gemms(
    const float* __restrict__ proj_w, const float* __restrict__ proj_Y,
    const float* __restrict__ fs_w, const float* __restrict__ fs_Y,
    const float* __restrict__ so3_w, const float* __restrict__ so3_D,
    float* __restrict__ wP, float* __restrict__ wSumP, float* __restrict__ wPsi2,
    float* __restrict__ wPsiP)
{
  __shared__ float smem[32*68*2];
  const int blk = blockIdx.x;
  const float is192 = 0.07216878364870323f;
  if (blk < 1) {
    dev_gemm_nn(smem, proj_w, proj_Y, wP, 49,49,192, 192,49,49, is192, 0, 0);
  } else if (blk < 9) {
    dev_gemm_nn(smem, so3_w, so3_D, wPsi2, 8,455,192, 192,455,455, is192, blk-1, 0);
  } else if (blk < 73) {
    dev_gemm_nn(smem, fs_w, fs_Y, wPsiP, 4096,49,192, 192,49,128, is192, 0, blk-9);
  } else {
    dev_sumP(smem, proj_w, proj_Y, wSumP);
  }
}

// B) the three weight transposes : 1280 blocks, 16.6 KB LDS
__global__ __launch_bounds__(256) void prep_t64(
    const float* __restrict__ conv_w, const float* __restrict__ act_to,
    const float* __restrict__ act_from,
    ushort_t* __restrict__ actToT, ushort_t* __restrict__ actFromT,
    ushort_t* __restrict__ cwT)
{
  __shared__ float smem[64*65];
  const int blk = blockIdx.x;
  if (blk < 512) {
    dev_transpose_cvt64(smem, act_to, 455, 4000, actToT, 512, 4096, blk & 63, blk >> 6);
  } else if (blk < 1024) {
    const int t = blk-512;  dev_transpose_cvt64(smem, act_from, 4000, 455, actFromT, 4096, 512, t & 7, t >> 3);
  } else {
    const int t = blk-1024; dev_transpose_cvt64(smem, conv_w, 512, 2048, cwT, 512, 2048, t & 31, t >> 5);
  }
}

// C) fmap transpose : 4096 blocks (64 ch x 1 batch each), 12.5 KB LDS.
// Store-phase LDS reads: bank = (4m+17j+g) mod 32 -> exactly 2 lanes/bank = free.
__global__ __launch_bounds__(256) void prep_fmap(
    const float* __restrict__ fmap, ushort_t* __restrict__ out)
{
  __shared__ float Fs[64*49];   // [c_local][h]
  const int tid = threadIdx.x;
  const int cc = blockIdx.x & 31, b = blockIdx.x >> 5;
  const int c0 = cc*64;
  const float* fsrc = fmap + ((size_t)b*CENC + c0)*HW;   // 3136 floats contiguous
  for (int idx = tid; idx < 784; idx += 256)
    *(float4*)&Fs[idx*4] = *(const float4*)&fsrc[idx*4];
  __syncthreads();
  for (int idx = tid; idx < 784; idx += 256) {           // 49 h * 16 groups of 4 channels
    const int h = idx >> 4, c4 = (idx & 15) * 4;
    unsigned int lo = (unsigned int)f2bf(Fs[(c4+0)*49 + h]) | ((unsigned int)f2bf(Fs[(c4+1)*49 + h]) << 16);
    unsigned int hi = (unsigned int)f2bf(Fs[(c4+2)*49 + h]) | ((unsigned int)f2bf(Fs[(c4+3)*49 + h]) << 16);
    *(uint2*)&out[(size_t)(b*49 + h)*CENC + c0 + c4] = make_uint2(lo, hi);
  }
}

// ============ psiT cvt + bpsi ============
__global__ __launch_bounds__(256) void psiT_bpsi(
    const float* __restrict__ wPsiP, const float* __restrict__ conv_b,
    ushort_t* __restrict__ psiT, float* __restrict__ bpsi)
{
  const int blk = blockIdx.x, tid = threadIdx.x;
  if (blk < 1024) {
    const int idx = blk*256 + tid;
    const int row = idx >> 9, f = idx & 511;
    const int g = row >> 6, ii = row & 63;
    psiT[idx] = (ii < 49) ? f2bf(wPsiP[(size_t)(f*8 + g)*128 + ii]) : (ushort_t)0;
  } else {
    const int w = tid >> 6, lane = tid & 63;
    const int gi = (blk-1024)*4 + w;
    const int g = gi >> 6, ii = gi & 63;
    float s = 0.f;
    if (ii < 49) {
      #pragma unroll
      for (int s8 = 0; s8 < 8; ++s8) {
        const int f = s8*64 + lane;
        s += conv_b[f] * bf2f(f2bf(wPsiP[(size_t)(f*8 + g)*128 + ii]));
      }
    }
    #pragma unroll
    for (int off = 32; off; off >>= 1) s += __shfl_down(s, off);
    if (lane == 0) bpsi[gi] = s;
  }
}

// ---------- bf16 MFMA NT GEMM, m97-style async staging ----------
// Tile M=64 x N=128, BK=64, 4 waves (256 thr), wave-tile 64x32 (acc[4][2]).
// mode 0: fp32 store | mode 1: relu->bf16 | mode 2: split-K fp32 partials | mode 3: bf16
__global__ __launch_bounds__(256) void gemm4_nt(
    const ushort_t* __restrict__ A, const ushort_t* __restrict__ B, void* __restrict__ Cv,
    int M, int N, int K, int lda, int ldb, int ldc,
    int mode, int kPartLen)
{
  __shared__ ushort_t Alds[64*64];    // 8 KB : 64 rows x 64 k
  __shared__ ushort_t Blds[128*64];   // 16 KB: 128 rows x 64 k
  const int tid = threadIdx.x;
  const int wv = tid >> 6, ln = tid & 63;
  const int col = ln & 15, quad = ln >> 4;
  const int m0 = blockIdx.y * 64, n0 = blockIdx.x * 128;
  int kStart = 0, kEnd = K;
  float*    C  = (float*)Cv;
  ushort_t* Cb = (ushort_t*)Cv;
  if (mode == 2) {
    kStart = blockIdx.z * kPartLen;
    kEnd = min(K, kStart + kPartLen);
    C += (size_t)blockIdx.z * (size_t)M * (size_t)ldc;
  }

  // staging addresses (advance by 64 elements per k-iter)
  const int rl = ln >> 3;          // row within 8-row group
  const int gsw = (ln & 7) ^ rl;   // swizzled granule to FETCH (row&7 == rl)
  const ushort_t* aP[2]; const ushort_t* bP[4];
  ushort_t* aL[2]; ushort_t* bL[4];
  #pragma unroll
  for (int r = 0; r < 2; ++r) {
    const int R = wv*16 + r*8;
    aP[r] = A + (size_t)(m0 + R + rl)*lda + kStart + gsw*8;
    aL[r] = &Alds[R*64];           // wave-uniform
  }
  #pragma unroll
  for (int r = 0; r < 4; ++r) {
    const int R = wv*32 + r*8;
    bP[r] = B + (size_t)(n0 + R + rl)*ldb + kStart + gsw*8;
    bL[r] = &Blds[R*64];
  }

  f32x4 acc[4][2];
  #pragma unroll
  for (int i = 0; i < 4; ++i)
    #pragma unroll
    for (int j = 0; j < 2; ++j)
      acc[i][j] = (f32x4){0.f,0.f,0.f,0.f};

  for (int k0 = kStart; k0 < kEnd; k0 += 64) {
    #pragma unroll
    for (int r = 0; r < 2; ++r) { GLD16(aP[r], aL[r]); aP[r] += 64; }
    #pragma unroll
    for (int r = 0; r < 4; ++r) { GLD16(bP[r], bL[r]); bP[r] += 64; }
    __syncthreads();
    #pragma unroll
    for (int ks = 0; ks < 2; ++ks) {
      bf16x8 af[4], bfr[2];
      #pragma unroll
      for (int i = 0; i < 4; ++i) {
        const int row = i*16 + col;
        af[i] = *(bf16x8*)&Alds[row*64 + (((ks*4 + quad) ^ (row & 7)) << 3)];
      }
      #pragma unroll
      for (int j = 0; j < 2; ++j) {
        const int row = wv*32 + j*16 + col;
        bfr[j] = *(bf16x8*)&Blds[row*64 + (((ks*4 + quad) ^ (row & 7)) << 3)];
      }
      #pragma unroll
      for (int i = 0; i < 4; ++i)
        #pragma unroll
        for (int j = 0; j < 2; ++j)
          acc[i][j] = __builtin_amdgcn_mfma_f32_16x16x32_bf16(af[i], bfr[j], acc[i][j], 0, 0, 0);
    }
    __syncthreads();
  }

  // epilogue: C/D layout col = lane&15 (n), row = quad*4 + reg (m)
  #pragma unroll
  for (int i = 0; i < 4; ++i) {
    const int mBase = m0 + i*16 + quad*4;
    #pragma unroll
    for (int j = 0; j < 2; ++j) {
      const int n = n0 + wv*32 + j*16 + col;
      if (mode == 1) {
        #pragma unroll
        for (int r = 0; r < 4; ++r)
          Cb[(size_t)(mBase+r)*ldc + n] = f2bf(fmaxf(acc[i][j][r], 0.f));
      } else if (mode == 3) {
        #pragma unroll
        for (int r = 0; r < 4; ++r)
          Cb[(size_t)(mBase+r)*ldc + n] = f2bf(acc[i][j][r]);
      } else {
        #pragma unroll
        for (int r = 0; r < 4; ++r)
          C[(size_t)(mBase+r)*ldc + n] = acc[i][j][r];
      }
    }
  }
}

// ---------- gather_y: P-contraction + block-diag gather + rank-1 bias + 1/sqrt(512) ----------
__global__ __launch_bounds__(256) void gather_y(
    const float* __restrict__ T, const float* __restrict__ P,
    const float* __restrict__ sumP, const float* __restrict__ bpsi,
    ushort_t* __restrict__ y)
{
  __shared__ float Tg[49*64];
  __shared__ float Pl[49*49];
  __shared__ float sPl[49];
  __shared__ float bps[64];
  const int tid = threadIdx.x;
  const int g = blockIdx.x & 7, b = blockIdx.x >> 3;
  for (int idx = tid; idx < 49*64; idx += 256) {
    const int h = idx >> 6, c = idx & 63;
    Tg[idx] = T[(size_t)(b*49 + h)*512 + g*64 + c];
  }
  for (int idx = tid; idx < 2401; idx += 256) Pl[idx] = P[idx];
  if (tid < 49) sPl[tid] = sumP[tid];
  if (tid < 64) bps[tid] = bpsi[g*64 + tid];
  __syncthreads();
  #pragma unroll
  for (int rr = 0; rr < 2; ++rr) {
    const int j = tid + rr*256;
    float v = 0.f;
    if (j < SO3D) {
      int l;
      if (j < 1) l = 0; else if (j < 10) l = 1; else if (j < 35) l = 2;
      else if (j < 84) l = 3; else if (j < 165) l = 4; else if (j < 286) l = 5; else l = 6;
      const int so = soff(l), d = 2*l+1;
      const int r = j - so;
      const int u = r / d, m = r - u*d;
      const int i = l*l + m, colT = l*l + u;
      float acc = 0.f;
      #pragma unroll 7
      for (int h = 0; h < 49; ++h)
        acc = fmaf(Pl[h*49 + i], Tg[h*64 + colT], acc);
      v = (acc + sPl[i]*bps[colT]) * 0.044194173824159216f;
    }
    y[(size_t)(b*8+g)*512 + j] = f2bf(v);
  }
}

// ---------- final so3 conv: 8-partial sum + per-l contraction + fp32 store ----------
__global__ __launch_bounds__(512) void so3_final(
    const float* __restrict__ zpart, const float* __restrict__ psi2,
    float* __restrict__ out)
{
  __shared__ float Zs[8*SO3D];
  __shared__ float P2s[8*SO3D];
  const int b = blockIdx.x, tid = threadIdx.x;
  for (int idx = tid; idx < 8*SO3D; idx += 512) {
    const int f = idx / SO3D, i = idx - f*SO3D;
    float s = 0.f;
    #pragma unroll
    for (int p = 0; p < 8; ++p)
      s += zpart[((size_t)p*1024 + (size_t)b*FHID + f)*512 + i];
    Zs[idx] = s;
    P2s[idx] = psi2[idx];
  }
  __syncthreads();
  if (tid < SO3D) {
    const int i = tid;
    int l;
    if (i < 1) l = 0; else if (i < 10) l = 1; else if (i < 35) l = 2;
    else if (i < 84) l = 3; else if (i < 165) l = 4; else if (i < 286) l = 5; else l = 6;
    const int so = soff(l), d = 2*l+1;
    const int r = i - so;
    const int v = r / d, m = r - v*d;
    float acc = 0.f;
    for (int f = 0; f < 8; ++f)
      for (int u = 0; u < d; ++u)
        acc = fmaf(Zs[f*SO3D + so + u*d + m], P2s[f*SO3D + so + u*d + v], acc);
    const float scale = rsqrtf(8.0f * (float)d);
    out[(size_t)b*SO3D + i] = acc * scale;
  }
}

extern "C" void kernel_launch(void* const* d_in, const int* in_sizes, int n_in,
                              void* d_out, int out_size, void* d_ws, size_t ws_size,
                              hipStream_t stream) {
  const float* fmap    = (const float*)d_in[0];
  const float* conv_w  = (const float*)d_in[1];
  const float* conv_b  = (const float*)d_in[2];
  const float* proj_w  = (const float*)d_in[3];
  const float* proj_Y  = (const float*)d_in[4];
  const float* fs_w    = (const float*)d_in[5];
  const float* fs_Y    = (const float*)d_in[6];
  const float* act_to  = (const float*)d_in[7];
  const float* act_from= (const float*)d_in[8];
  const float* so3_w   = (const float*)d_in[9];
  const float* so3_D   = (const float*)d_in[10];
  float* out           = (float*)d_out;

  // workspace (bytes), lifetime-packed; max ~54.8 MB (known-good size)
  char* wsb = (char*)d_ws;
  float*    wP       = (float*)(wsb + 0);           // 49x49 fp32
  float*    wSumP    = (float*)(wsb + 9728);        // 64 fp32
  float*    wPsi2    = (float*)(wsb + 9984);        // 8x455 fp32 -> 24544, pad 24576
  ushort_t* actToT   = (ushort_t*)(wsb + 24576);    // 4096x512 bf16 -> 4218880
  ushort_t* actFromT = (ushort_t*)(wsb + 4218880);  // 512x4096 bf16 -> 8413184
  ushort_t* yPad     = (ushort_t*)(wsb + 8413184);  // 1024x512 bf16 -> 9461760
  ushort_t* psiT     = (ushort_t*)(wsb + 9461760);  // 512x512 bf16 -> 9986048
  float*    bpsi     = (float*)(wsb + 9986048);     // 512 fp32 -> 9988096
  ushort_t* W2T      = (ushort_t*)(wsb + 9988096);  // 512x2048 bf16 -> 12085248
  ushort_t* fmapT    = (ushort_t*)(wsb + 12085248); // 6272x2048 bf16 -> 37775360 (dead after T gemm)
  float*    wPsiP    = (float*)(wsb + 37775360);    // 4096x128 fp32 -> 39872512 (dead after psiT_bpsi)
  ushort_t* cwT      = (ushort_t*)(wsb + 39872512); // 2048x512 bf16 -> 41969664 (dead after W2T gemm)
  float*    Tbuf     = (float*)(wsb + 41969664);    // 6272x512 fp32 -> 54814720
  // aliases into dead fmapT region:
  ushort_t* gBuf     = (ushort_t*)(wsb + 12085248); // 1024x4096 bf16 -> 20473856
  float*    zPart    = (float*)(wsb + 20473856);    // 8x1024x512 fp32 -> 37251072

  // 1) prep, split into homogeneous kernels (was one 45us mega-kernel)
  prep_fmap <<<dim3(4096), 256, 0, stream>>>(fmap, fmapT);
  prep_t64  <<<dim3(1280), 256, 0, stream>>>(conv_w, act_to, act_from, actToT, actFromT, cwT);
  prep_gemms<<<dim3(74),   256, 0, stream>>>(proj_w, proj_Y, fs_w, fs_Y, so3_w, so3_D,
                                             wP, wSumP, wPsi2, wPsiP);
  // 2) psiT cvt + bpsi
  psiT_bpsi<<<dim3(1152), 256, 0, stream>>>(wPsiP, conv_b, psiT, bpsi);
  // 3) W2T[gi][c] = psiT @ cwT^T   (M=512, N=2048, K=512), bf16 out
  gemm4_nt<<<dim3(16,8), 256, 0, stream>>>(psiT, cwT, W2T,
      512, 2048, 512, 512, 512, 2048, 3, 0);
  // 4) T[(b,h)][gi] = fmapT @ W2T^T  (M=6272, N=512, K=2048), fp32 out, grid 4x98
  gemm4_nt<<<dim3(4,98), 256, 0, stream>>>(fmapT, W2T, Tbuf,
      6272, 512, 2048, 2048, 2048, 512, 0, 0);
  // 5) yPad = P-contraction + block-diag gather + rank-1 bias + 1/sqrt(512)
  gather_y<<<dim3(1024), 256, 0, stream>>>(Tbuf, wP, wSumP, bpsi, yPad);
  // 6) g = relu(yPad @ actToT^T) bf16   (M=1024, N=4096, K=512)
  gemm4_nt<<<dim3(32,16), 256, 0, stream>>>(yPad, actToT, gBuf,
      1024, 4096, 512, 512, 512, 4096, 1, 0);
  // 7) zPart = gBuf @ actFromT^T, split-K=8 partial buffers  (M=1024, N=512, K=4096)
  gemm4_nt<<<dim3(4,16,8), 256, 0, stream>>>(gBuf, actFromT, zPart,
      1024, 512, 4096, 4096, 4096, 512, 2, 512);
  // 8) final contraction + fp32 store
  so3_final<<<dim3(128), 512, 0, stream>>>(zPart, wPsi2, out);
}

// Round 3
// 242.798 us; speedup vs baseline: 1.0261x; 1.0261x over previous
//
#include <hip/hip_runtime.h>
#include <hip/hip_bf16.h>

#define NB    128
#define CENC  2048
#define FIN   512
#define FHID  8
#define S2D   49
#define SO3D  455
#define HW    49

typedef unsigned short ushort_t;
typedef __bf16 bf16x8 __attribute__((ext_vector_type(8)));
typedef float  f32x4  __attribute__((ext_vector_type(4)));

// async global->LDS, 16B per lane; LDS dest = wave-uniform base + lane*16
#define GLD16(gp, lp) __builtin_amdgcn_global_load_lds( \
    (__attribute__((address_space(1))) const unsigned int*)(gp), \
    (__attribute__((address_space(3))) unsigned int*)(lp), 16, 0, 0)

__device__ __forceinline__ int soff(int l) { return l*(4*l*l-1)/3; }  // sum_{l'<l}(2l'+1)^2

__device__ __forceinline__ ushort_t f2bf(float x) {
  __hip_bfloat16 h = __float2bfloat16(x);
  return *reinterpret_cast<ushort_t*>(&h);
}
__device__ __forceinline__ float bf2f(ushort_t u) {
  __hip_bfloat16 h = *reinterpret_cast<__hip_bfloat16*>(&u);
  return __bfloat162float(h);
}

// ================= device building blocks for the fused prep kernel =================

// cmode 0: C store fp32*alpha. cmode 1: psiT store — psiTout[(g*64+n)*512 + f] = bf16,
// f=m>>3, g=m&7, zero-padded for n in [49,64).
__device__ __forceinline__ void dev_gemm_nn(float* smem,
    const float* __restrict__ A, const float* __restrict__ B, float* __restrict__ C,
    int M, int N, int K, int lda, int ldb, int ldc, float alpha, int bx, int by,
    int cmode, ushort_t* __restrict__ psiTout)
{
  float* As = smem;
  float* Bs = smem + 32*68;
  const int tid = threadIdx.x;
  const int tx = tid & 15, ty = tid >> 4;
  const int n0 = bx * 64, m0 = by * 64;
  float acc[4][4] = {};
  for (int k0 = 0; k0 < K; k0 += 32) {
    {
      const int kk = tid & 31, mmB = tid >> 5;
      #pragma unroll
      for (int j = 0; j < 8; ++j) {
        const int mm = mmB + 8*j;
        const int m = m0 + mm, k = k0 + kk;
        As[kk*68 + mm] = (m < M && k < K) ? A[(size_t)m*lda + k] : 0.f;
      }
    }
    {
      const int nn = tid & 63, kkB = tid >> 6;
      #pragma unroll
      for (int j = 0; j < 8; ++j) {
        const int kk = kkB + 4*j;
        const int n = n0 + nn, k = k0 + kk;
        Bs[kk*68 + nn] = (n < N && k < K) ? B[(size_t)k*ldb + n] : 0.f;
      }
    }
    __syncthreads();
    #pragma unroll
    for (int kk = 0; kk < 32; ++kk) {
      const float4 a4 = *(const float4*)&As[kk*68 + ty*4];
      const float4 b4 = *(const float4*)&Bs[kk*68 + tx*4];
      const float av[4] = {a4.x,a4.y,a4.z,a4.w};
      const float bv[4] = {b4.x,b4.y,b4.z,b4.w};
      #pragma unroll
      for (int i = 0; i < 4; ++i)
        #pragma unroll
        for (int j = 0; j < 4; ++j)
          acc[i][j] = fmaf(av[i], bv[j], acc[i][j]);
    }
    __syncthreads();
  }
  if (cmode == 1) {
    #pragma unroll
    for (int i = 0; i < 4; ++i) {
      const int m = m0 + ty*4 + i;          // m = f*8+g, always < 4096 here
      const int f = m >> 3, g = m & 7;
      #pragma unroll
      for (int j = 0; j < 4; ++j) {
        const int n = tx*4 + j;             // 0..63 — covers full pad range
        psiTout[(size_t)(g*64 + n)*512 + f] = (n < 49) ? f2bf(acc[i][j]*alpha) : (ushort_t)0;
      }
    }
    return;
  }
  #pragma unroll
  for (int i = 0; i < 4; ++i) {
    const int m = m0 + ty*4 + i;
    if (m >= M) continue;
    #pragma unroll
    for (int j = 0; j < 4; ++j) {
      const int n = n0 + tx*4 + j;
      if (n >= N) continue;
      C[(size_t)m*ldc + n] = acc[i][j] * alpha;
    }
  }
}

// 64x64 transpose + fp32->bf16 cvt, packed 8B stores.
// out[c*Rp + r] = bf16(in[r*C + c]), zero-padded to (Cp, Rp).
__device__ __forceinline__ void dev_transpose_cvt64(float* smem,
    const float* __restrict__ in, int R, int C,
    ushort_t* __restrict__ out, int Rp, int Cp, int bx, int by)
{
  float (*t)[65] = (float(*)[65])smem;         // 64x65 fp32
  const int c0 = bx*64, r0 = by*64;
  const int tid = threadIdx.x;
  const int cl = tid & 63, rlB = tid >> 6;
  #pragma unroll
  for (int p = 0; p < 16; ++p) {
    const int rl = rlB + p*4;
    const int r = r0 + rl, c = c0 + cl;
    t[rl][cl] = (r < R && c < C) ? in[(size_t)r*C + c] : 0.f;
  }
  __syncthreads();
  #pragma unroll
  for (int p = 0; p < 4; ++p) {
    const int c = p*16 + (tid >> 4);
    const int r4 = (tid & 15) * 4;
    unsigned int lo = (unsigned int)f2bf(t[r4+0][c]) | ((unsigned int)f2bf(t[r4+1][c]) << 16);
    unsigned int hi = (unsigned int)f2bf(t[r4+2][c]) | ((unsigned int)f2bf(t[r4+3][c]) << 16);
    *(uint2*)&out[(size_t)(c0 + c)*Rp + r0 + r4] = make_uint2(lo, hi);
  }
}

// fmap transpose: 64 channels x 49 hw of one batch b; packed 8B bf16 stores.
__device__ __forceinline__ void dev_transpose_fmap(float* smem,
    const float* __restrict__ fmap, ushort_t* __restrict__ out, int cc, int b)
{
  float* Fs = smem;   // [c_local][h], 64*49
  const int tid = threadIdx.x;
  const int c0 = cc*64;
  const float* fsrc = fmap + ((size_t)b*CENC + c0)*HW;   // 3136 floats contiguous
  for (int idx = tid; idx < 784; idx += 256)
    *(float4*)&Fs[idx*4] = *(const float4*)&fsrc[idx*4];
  __syncthreads();
  for (int idx = tid; idx < 784; idx += 256) {           // 49 h * 16 groups of 4 channels
    const int h = idx >> 4, c4 = (idx & 15) * 4;
    unsigned int lo = (unsigned int)f2bf(Fs[(c4+0)*49 + h]) | ((unsigned int)f2bf(Fs[(c4+1)*49 + h]) << 16);
    unsigned int hi = (unsigned int)f2bf(Fs[(c4+2)*49 + h]) | ((unsigned int)f2bf(Fs[(c4+3)*49 + h]) << 16);
    *(uint2*)&out[(size_t)(b*49 + h)*CENC + c0 + c4] = make_uint2(lo, hi);
  }
}

__device__ __forceinline__ void dev_sumP(float* smem,
    const float* __restrict__ proj_w, const float* __restrict__ proj_Y,
    float* __restrict__ sumP)
{
  float* colsum = smem;   // 192 floats
  const int tid = threadIdx.x;
  if (tid < 192) {
    float s = 0.f;
    for (int h = 0; h < 49; ++h) s += proj_w[h*192 + tid];
    colsum[tid] = s;
  }
  __syncthreads();
  if (tid < 64) {
    float s = 0.f;
    if (tid < 49) for (int k = 0; k < 192; ++k) s += colsum[k] * proj_Y[k*49 + tid];
    sumP[tid] = (tid < 49) ? s * 0.07216878364870323f : 0.f;
  }
}

// ================= fused prep kernel (single dispatch, max overlap) =================
__global__ __launch_bounds__(256) void prep_all(
    const float* __restrict__ fmap, const float* __restrict__ conv_w,
    const float* __restrict__ proj_w, const float* __restrict__ proj_Y,
    const float* __restrict__ fs_w, const float* __restrict__ fs_Y,
    const float* __restrict__ act_to, const float* __restrict__ act_from,
    const float* __restrict__ so3_w, const float* __restrict__ so3_D,
    float* __restrict__ wP, float* __restrict__ wSumP, float* __restrict__ wPsi2,
    ushort_t* __restrict__ psiT,
    ushort_t* __restrict__ actToT, ushort_t* __restrict__ actFromT,
    ushort_t* __restrict__ cwT, ushort_t* __restrict__ fmapT)
{
  __shared__ float smem[4352];   // 17408 B: gemm 4352, cvt64 4160, fmap 3136
  const int blk = blockIdx.x;
  const float is192 = 0.07216878364870323f;
  if (blk < 1) {
    dev_gemm_nn(smem, proj_w, proj_Y, wP, 49,49,192, 192,49,49, is192, 0, 0, 0, nullptr);
  } else if (blk < 9) {
    dev_gemm_nn(smem, so3_w, so3_D, wPsi2, 8,455,192, 192,455,455, is192, blk-1, 0, 0, nullptr);
  } else if (blk < 73) {
    // fs_w GEMM -> writes psiT (bf16, transposed, padded) directly
    dev_gemm_nn(smem, fs_w, fs_Y, nullptr, 4096,49,192, 192,49,0, is192, 0, blk-9, 1, psiT);
  } else if (blk < 585) {
    const int t = blk-73;   dev_transpose_cvt64(smem, act_to, 455, 4000, actToT, 512, 4096, t & 63, t >> 6);
  } else if (blk < 1097) {
    const int t = blk-585;  dev_transpose_cvt64(smem, act_from, 4000, 455, actFromT, 4096, 512, t & 7, t >> 3);
  } else if (blk < 1353) {
    const int t = blk-1097; dev_transpose_cvt64(smem, conv_w, 512, 2048, cwT, 512, 2048, t & 31, t >> 5);
  } else if (blk < 5449) {
    const int t = blk-1353; dev_transpose_fmap(smem, fmap, fmapT, t & 31, t >> 5);
  } else {
    dev_sumP(smem, proj_w, proj_Y, wSumP);
  }
}

// ---------- W2T GEMM (64x128 tile) + bpsi side-product ----------
// W2T[gi][c] = sum_f psiT[gi][f] * cwT[c][f]; bx==0 blocks also compute
// bpsi[gi] = sum_f conv_b[f] * psiT[gi][f] from the staged A tiles.
__global__ __launch_bounds__(256) void gemm_w2t(
    const ushort_t* __restrict__ A, const ushort_t* __restrict__ B,
    const float* __restrict__ conv_b,
    ushort_t* __restrict__ Cb, float* __restrict__ bpsi)
{
  __shared__ ushort_t Alds[64*64];
  __shared__ ushort_t Blds[128*64];
  __shared__ float bred[256];
  const int tid = threadIdx.x;
  const int wv = tid >> 6, ln = tid & 63;
  const int col = ln & 15, quad = ln >> 4;
  const int m0 = blockIdx.y * 64, n0 = blockIdx.x * 128;
  const int lda = 512, ldb = 512, ldc = 2048, K = 512;
  const bool doB = (blockIdx.x == 0);
  const int br = tid & 63, bp = tid >> 6;   // bpsi: row, granule-pair

  const int rl = ln >> 3;
  const int gsw = (ln & 7) ^ rl;
  const ushort_t* aP[2]; const ushort_t* bP[4];
  ushort_t* aL[2]; ushort_t* bL[4];
  #pragma unroll
  for (int r = 0; r < 2; ++r) {
    const int R = wv*16 + r*8;
    aP[r] = A + (size_t)(m0 + R + rl)*lda + gsw*8;
    aL[r] = &Alds[R*64];
  }
  #pragma unroll
  for (int r = 0; r < 4; ++r) {
    const int R = wv*32 + r*8;
    bP[r] = B + (size_t)(n0 + R + rl)*ldb + gsw*8;
    bL[r] = &Blds[R*64];
  }

  f32x4 acc[4][2];
  #pragma unroll
  for (int i = 0; i < 4; ++i)
    #pragma unroll
    for (int j = 0; j < 2; ++j)
      acc[i][j] = (f32x4){0.f,0.f,0.f,0.f};
  float bacc = 0.f;

  for (int k0 = 0; k0 < K; k0 += 64) {
    #pragma unroll
    for (int r = 0; r < 2; ++r) { GLD16(aP[r], aL[r]); aP[r] += 64; }
    #pragma unroll
    for (int r = 0; r < 4; ++r) { GLD16(bP[r], bL[r]); bP[r] += 64; }
    __syncthreads();
    #pragma unroll
    for (int ks = 0; ks < 2; ++ks) {
      bf16x8 af[4], bfr[2];
      #pragma unroll
      for (int i = 0; i < 4; ++i) {
        const int row = i*16 + col;
        af[i] = *(bf16x8*)&Alds[row*64 + (((ks*4 + quad) ^ (row & 7)) << 3)];
      }
      #pragma unroll
      for (int j = 0; j < 2; ++j) {
        const int row = wv*32 + j*16 + col;
        bfr[j] = *(bf16x8*)&Blds[row*64 + (((ks*4 + quad) ^ (row & 7)) << 3)];
      }
      #pragma unroll
      for (int i = 0; i < 4; ++i)
        #pragma unroll
        for (int j = 0; j < 2; ++j)
          acc[i][j] = __builtin_amdgcn_mfma_f32_16x16x32_bf16(af[i], bfr[j], acc[i][j], 0, 0, 0);
    }
    if (doB) {
      // accumulate conv_b . A over this K-tile from staged LDS
      #pragma unroll
      for (int qq = 0; qq < 2; ++qq) {
        const int q = bp*2 + qq;
        const int lo = (q ^ (br & 7)) << 3;
        #pragma unroll
        for (int e = 0; e < 8; ++e)
          bacc = fmaf(conv_b[k0 + q*8 + e], bf2f(Alds[br*64 + lo + e]), bacc);
      }
    }
    __syncthreads();
  }

  #pragma unroll
  for (int i = 0; i < 4; ++i) {
    const int mBase = m0 + i*16 + quad*4;
    #pragma unroll
    for (int j = 0; j < 2; ++j) {
      const int n = n0 + wv*32 + j*16 + col;
      #pragma unroll
      for (int r = 0; r < 4; ++r)
        Cb[(size_t)(mBase+r)*ldc + n] = f2bf(acc[i][j][r]);
    }
  }
  if (doB) {
    bred[bp*64 + br] = bacc;
    __syncthreads();
    if (tid < 64)
      bpsi[m0 + tid] = bred[tid] + bred[64+tid] + bred[128+tid] + bred[192+tid];
  }
}

// ---------- bf16 MFMA NT GEMM, 128x128 tile (m97 geometry), BK=64 ----------
// 4 waves in 2x2; each wave 64x64 (acc[4][4]); 32 MFMA/wave per K-step.
// mode 0: fp32 store | mode 1: relu->bf16 | mode 2: split-K fp32 partials
__global__ __launch_bounds__(256) void gemm8_nt(
    const ushort_t* __restrict__ A, const ushort_t* __restrict__ B, void* __restrict__ Cv,
    int M, int N, int K, int lda, int ldb, int ldc,
    int mode, int kPartLen)
{
  __shared__ ushort_t Alds[128*64];   // 16 KB
  __shared__ ushort_t Blds[128*64];   // 16 KB
  const int tid = threadIdx.x;
  const int wv = tid >> 6, ln = tid & 63;
  const int col = ln & 15, quad = ln >> 4;
  const int wr = wv >> 1, wc = wv & 1;
  const int m0 = blockIdx.y * 128, n0 = blockIdx.x * 128;
  int kStart = 0, kEnd = K;
  float*    C  = (float*)Cv;
  ushort_t* Cb = (ushort_t*)Cv;
  if (mode == 2) {
    kStart = blockIdx.z * kPartLen;
    kEnd = min(K, kStart + kPartLen);
    C += (size_t)blockIdx.z * (size_t)M * (size_t)ldc;
  }

  const int rl = ln >> 3;          // row within 8-row group
  const int gsw = (ln & 7) ^ rl;   // swizzled granule to FETCH
  const ushort_t* aP[4]; const ushort_t* bP[4];
  ushort_t* aL[4]; ushort_t* bL[4];
  #pragma unroll
  for (int r = 0; r < 4; ++r) {
    const int R = r*32 + wv*8;
    aP[r] = A + (size_t)(m0 + R + rl)*lda + kStart + gsw*8;
    aL[r] = &Alds[R*64];           // wave-uniform
    bP[r] = B + (size_t)(n0 + R + rl)*ldb + kStart + gsw*8;
    bL[r] = &Blds[R*64];
  }

  f32x4 acc[4][4];
  #pragma unroll
  for (int i = 0; i < 4; ++i)
    #pragma unroll
    for (int j = 0; j < 4; ++j)
      acc[i][j] = (f32x4){0.f,0.f,0.f,0.f};

  for (int k0 = kStart; k0 < kEnd; k0 += 64) {
    #pragma unroll
    for (int r = 0; r < 4; ++r) { GLD16(aP[r], aL[r]); aP[r] += 64; }
    #pragma unroll
    for (int r = 0; r < 4; ++r) { GLD16(bP[r], bL[r]); bP[r] += 64; }
    __syncthreads();
    #pragma unroll
    for (int ks = 0; ks < 2; ++ks) {
      bf16x8 af[4], bfr[4];
      #pragma unroll
      for (int i = 0; i < 4; ++i) {
        const int row = wr*64 + i*16 + col;
        af[i] = *(bf16x8*)&Alds[row*64 + (((ks*4 + quad) ^ (row & 7)) << 3)];
      }
      #pragma unroll
      for (int j = 0; j < 4; ++j) {
        const int row = wc*64 + j*16 + col;
        bfr[j] = *(bf16x8*)&Blds[row*64 + (((ks*4 + quad) ^ (row & 7)) << 3)];
      }
      #pragma unroll
      for (int i = 0; i < 4; ++i)
        #pragma unroll
        for (int j = 0; j < 4; ++j)
          acc[i][j] = __builtin_amdgcn_mfma_f32_16x16x32_bf16(af[i], bfr[j], acc[i][j], 0, 0, 0);
    }
    __syncthreads();
  }

  // epilogue: C/D layout col = lane&15 (n), row = quad*4 + reg (m)
  #pragma unroll
  for (int i = 0; i < 4; ++i) {
    const int mBase = m0 + wr*64 + i*16 + quad*4;
    #pragma unroll
    for (int j = 0; j < 4; ++j) {
      const int n = n0 + wc*64 + j*16 + col;
      if (mode == 1) {
        #pragma unroll
        for (int r = 0; r < 4; ++r)
          Cb[(size_t)(mBase+r)*ldc + n] = f2bf(fmaxf(acc[i][j][r], 0.f));
      } else if (mode == 2 || mode == 0) {
        #pragma unroll
        for (int r = 0; r < 4; ++r)
          C[(size_t)(mBase+r)*ldc + n] = acc[i][j][r];
      }
    }
  }
}

// ---------- gather_y: P-contraction + block-diag gather + rank-1 bias + 1/sqrt(512) ----------
__global__ __launch_bounds__(256) void gather_y(
    const float* __restrict__ T, const float* __restrict__ P,
    const float* __restrict__ sumP, const float* __restrict__ bpsi,
    ushort_t* __restrict__ y)
{
  __shared__ float Tg[49*64];
  __shared__ float Pl[49*49];
  __shared__ float sPl[49];
  __shared__ float bps[64];
  const int tid = threadIdx.x;
  const int g = blockIdx.x & 7, b = blockIdx.x >> 3;
  for (int idx = tid; idx < 49*64; idx += 256) {
    const int h = idx >> 6, c = idx & 63;
    Tg[idx] = T[(size_t)(b*49 + h)*512 + g*64 + c];
  }
  for (int idx = tid; idx < 2401; idx += 256) Pl[idx] = P[idx];
  if (tid < 49) sPl[tid] = sumP[tid];
  if (tid < 64) bps[tid] = bpsi[g*64 + tid];
  __syncthreads();
  #pragma unroll
  for (int rr = 0; rr < 2; ++rr) {
    const int j = tid + rr*256;
    float v = 0.f;
    if (j < SO3D) {
      int l;
      if (j < 1) l = 0; else if (j < 10) l = 1; else if (j < 35) l = 2;
      else if (j < 84) l = 3; else if (j < 165) l = 4; else if (j < 286) l = 5; else l = 6;
      const int so = soff(l), d = 2*l+1;
      const int r = j - so;
      const int u = r / d, m = r - u*d;
      const int i = l*l + m, colT = l*l + u;
      float acc = 0.f;
      #pragma unroll 7
      for (int h = 0; h < 49; ++h)
        acc = fmaf(Pl[h*49 + i], Tg[h*64 + colT], acc);
      v = (acc + sPl[i]*bps[colT]) * 0.044194173824159216f;
    }
    y[(size_t)(b*8+g)*512 + j] = f2bf(v);
  }
}

// ---------- final so3 conv: 8-partial sum + per-l contraction + fp32 store ----------
__global__ __launch_bounds__(512) void so3_final(
    const float* __restrict__ zpart, const float* __restrict__ psi2,
    float* __restrict__ out)
{
  __shared__ float Zs[8*SO3D];
  __shared__ float P2s[8*SO3D];
  const int b = blockIdx.x, tid = threadIdx.x;
  for (int idx = tid; idx < 8*SO3D; idx += 512) {
    const int f = idx / SO3D, i = idx - f*SO3D;
    float s = 0.f;
    #pragma unroll
    for (int p = 0; p < 8; ++p)
      s += zpart[((size_t)p*1024 + (size_t)b*FHID + f)*512 + i];
    Zs[idx] = s;
    P2s[idx] = psi2[idx];
  }
  __syncthreads();
  if (tid < SO3D) {
    const int i = tid;
    int l;
    if (i < 1) l = 0; else if (i < 10) l = 1; else if (i < 35) l = 2;
    else if (i < 84) l = 3; else if (i < 165) l = 4; else if (i < 286) l = 5; else l = 6;
    const int so = soff(l), d = 2*l+1;
    const int r = i - so;
    const int v = r / d, m = r - v*d;
    float acc = 0.f;
    for (int f = 0; f < 8; ++f)
      for (int u = 0; u < d; ++u)
        acc = fmaf(Zs[f*SO3D + so + u*d + m], P2s[f*SO3D + so + u*d + v], acc);
    const float scale = rsqrtf(8.0f * (float)d);
    out[(size_t)b*SO3D + i] = acc * scale;
  }
}

extern "C" void kernel_launch(void* const* d_in, const int* in_sizes, int n_in,
                              void* d_out, int out_size, void* d_ws, size_t ws_size,
                              hipStream_t stream) {
  const float* fmap    = (const float*)d_in[0];
  const float* conv_w  = (const float*)d_in[1];
  const float* conv_b  = (const float*)d_in[2];
  const float* proj_w  = (const float*)d_in[3];
  const float* proj_Y  = (const float*)d_in[4];
  const float* fs_w    = (const float*)d_in[5];
  const float* fs_Y    = (const float*)d_in[6];
  const float* act_to  = (const float*)d_in[7];
  const float* act_from= (const float*)d_in[8];
  const float* so3_w   = (const float*)d_in[9];
  const float* so3_D   = (const float*)d_in[10];
  float* out           = (float*)d_out;

  // workspace (bytes), lifetime-packed; max ~54.8 MB (known-good size)
  char* wsb = (char*)d_ws;
  float*    wP       = (float*)(wsb + 0);           // 49x49 fp32
  float*    wSumP    = (float*)(wsb + 9728);        // 64 fp32
  float*    wPsi2    = (float*)(wsb + 9984);        // 8x455 fp32 -> 24544, pad 24576
  ushort_t* actToT   = (ushort_t*)(wsb + 24576);    // 4096x512 bf16 -> 4218880
  ushort_t* actFromT = (ushort_t*)(wsb + 4218880);  // 512x4096 bf16 -> 8413184
  ushort_t* yPad     = (ushort_t*)(wsb + 8413184);  // 1024x512 bf16 -> 9461760
  ushort_t* psiT     = (ushort_t*)(wsb + 9461760);  // 512x512 bf16 -> 9986048
  float*    bpsi     = (float*)(wsb + 9986048);     // 512 fp32 -> 9988096
  ushort_t* W2T      = (ushort_t*)(wsb + 9988096);  // 512x2048 bf16 -> 12085248
  ushort_t* fmapT    = (ushort_t*)(wsb + 12085248); // 6272x2048 bf16 -> 37775360 (dead after T gemm)
  ushort_t* cwT      = (ushort_t*)(wsb + 39872512); // 2048x512 bf16 -> 41969664 (dead after W2T gemm)
  float*    Tbuf     = (float*)(wsb + 41969664);    // 6272x512 fp32 -> 54814720
  // aliases into dead fmapT region:
  ushort_t* gBuf     = (ushort_t*)(wsb + 12085248); // 1024x4096 bf16 -> 20473856
  float*    zPart    = (float*)(wsb + 20473856);    // 8x1024x512 fp32 -> 37251072

  // 1) ALL independent prep in one dispatch; fs_w GEMM emits psiT directly
  prep_all<<<dim3(5450), 256, 0, stream>>>(
      fmap, conv_w, proj_w, proj_Y, fs_w, fs_Y, act_to, act_from, so3_w, so3_D,
      wP, wSumP, wPsi2, psiT, actToT, actFromT, cwT, fmapT);
  // 2) W2T[gi][c] = psiT @ cwT^T (M=512,N=2048,K=512) bf16; bx==0 also emits bpsi
  gemm_w2t<<<dim3(16,8), 256, 0, stream>>>(psiT, cwT, conv_b, W2T, bpsi);
  // 3) T[(b,h)][gi] = fmapT @ W2T^T  (M=6272, N=512, K=2048), fp32, 128^2 tiles
  gemm8_nt<<<dim3(4,49), 256, 0, stream>>>(fmapT, W2T, Tbuf,
      6272, 512, 2048, 2048, 2048, 512, 0, 0);
  // 4) yPad = P-contraction + block-diag gather + rank-1 bias + 1/sqrt(512)
  gather_y<<<dim3(1024), 256, 0, stream>>>(Tbuf, wP, wSumP, bpsi, yPad);
  // 5) g = relu(yPad @ actToT^T) bf16   (M=1024, N=4096, K=512), 128^2 tiles
  gemm8_nt<<<dim3(32,8), 256, 0, stream>>>(yPad, actToT, gBuf,
      1024, 4096, 512, 512, 512, 4096, 1, 0);
  // 6) zPart = gBuf @ actFromT^T, split-K=8  (M=1024, N=512, K=4096), 128^2 tiles
  gemm8_nt<<<dim3(4,8,8), 256, 0, stream>>>(gBuf, actFromT, zPart,
      1024, 512, 4096, 4096, 4096, 512, 2, 512);
  // 7) final contraction + fp32 store
  so3_final<<<dim3(128), 512, 0, stream>>>(zPart, wPsi2, out);
}

// Round 4
// 229.913 us; speedup vs baseline: 1.0836x; 1.0560x over previous
//
#include <hip/hip_runtime.h>
#include <hip/hip_bf16.h>

#define NB    128
#define CENC  2048
#define FIN   512
#define FHID  8
#define S2D   49
#define SO3D  455
#define HW    49

typedef unsigned short ushort_t;
typedef __bf16 bf16x8 __attribute__((ext_vector_type(8)));
typedef float  f32x4  __attribute__((ext_vector_type(4)));

// async global->LDS, 16B per lane; LDS dest = wave-uniform base + lane*16
#define GLD16(gp, lp) __builtin_amdgcn_global_load_lds( \
    (__attribute__((address_space(1))) const unsigned int*)(gp), \
    (__attribute__((address_space(3))) unsigned int*)(lp), 16, 0, 0)

__device__ __forceinline__ int soff(int l) { return l*(4*l*l-1)/3; }  // sum_{l'<l}(2l'+1)^2

__device__ __forceinline__ ushort_t f2bf(float x) {
  __hip_bfloat16 h = __float2bfloat16(x);
  return *reinterpret_cast<ushort_t*>(&h);
}
__device__ __forceinline__ float bf2f(ushort_t u) {
  __hip_bfloat16 h = *reinterpret_cast<__hip_bfloat16*>(&u);
  return __bfloat162float(h);
}

// ================= device building blocks for the fused prep kernel =================

// cmode 0: C store fp32*alpha. cmode 1: psiT store — psiTout[(g*64+n)*512 + f] = bf16,
// f=m>>3, g=m&7, zero-padded for n in [49,64).
__device__ __forceinline__ void dev_gemm_nn(float* smem,
    const float* __restrict__ A, const float* __restrict__ B, float* __restrict__ C,
    int M, int N, int K, int lda, int ldb, int ldc, float alpha, int bx, int by,
    int cmode, ushort_t* __restrict__ psiTout)
{
  float* As = smem;
  float* Bs = smem + 32*68;
  const int tid = threadIdx.x;
  const int tx = tid & 15, ty = tid >> 4;
  const int n0 = bx * 64, m0 = by * 64;
  float acc[4][4] = {};
  for (int k0 = 0; k0 < K; k0 += 32) {
    {
      const int kk = tid & 31, mmB = tid >> 5;
      #pragma unroll
      for (int j = 0; j < 8; ++j) {
        const int mm = mmB + 8*j;
        const int m = m0 + mm, k = k0 + kk;
        As[kk*68 + mm] = (m < M && k < K) ? A[(size_t)m*lda + k] : 0.f;
      }
    }
    {
      const int nn = tid & 63, kkB = tid >> 6;
      #pragma unroll
      for (int j = 0; j < 8; ++j) {
        const int kk = kkB + 4*j;
        const int n = n0 + nn, k = k0 + kk;
        Bs[kk*68 + nn] = (n < N && k < K) ? B[(size_t)k*ldb + n] : 0.f;
      }
    }
    __syncthreads();
    #pragma unroll
    for (int kk = 0; kk < 32; ++kk) {
      const float4 a4 = *(const float4*)&As[kk*68 + ty*4];
      const float4 b4 = *(const float4*)&Bs[kk*68 + tx*4];
      const float av[4] = {a4.x,a4.y,a4.z,a4.w};
      const float bv[4] = {b4.x,b4.y,b4.z,b4.w};
      #pragma unroll
      for (int i = 0; i < 4; ++i)
        #pragma unroll
        for (int j = 0; j < 4; ++j)
          acc[i][j] = fmaf(av[i], bv[j], acc[i][j]);
    }
    __syncthreads();
  }
  if (cmode == 1) {
    #pragma unroll
    for (int i = 0; i < 4; ++i) {
      const int m = m0 + ty*4 + i;          // m = f*8+g, always < 4096 here
      const int f = m >> 3, g = m & 7;
      #pragma unroll
      for (int j = 0; j < 4; ++j) {
        const int n = tx*4 + j;             // 0..63 — covers full pad range
        psiTout[(size_t)(g*64 + n)*512 + f] = (n < 49) ? f2bf(acc[i][j]*alpha) : (ushort_t)0;
      }
    }
    return;
  }
  #pragma unroll
  for (int i = 0; i < 4; ++i) {
    const int m = m0 + ty*4 + i;
    if (m >= M) continue;
    #pragma unroll
    for (int j = 0; j < 4; ++j) {
      const int n = n0 + tx*4 + j;
      if (n >= N) continue;
      C[(size_t)m*ldc + n] = acc[i][j] * alpha;
    }
  }
}

// 64x64 transpose + fp32->bf16 cvt, packed 8B stores.
__device__ __forceinline__ void dev_transpose_cvt64(float* smem,
    const float* __restrict__ in, int R, int C,
    ushort_t* __restrict__ out, int Rp, int Cp, int bx, int by)
{
  float (*t)[65] = (float(*)[65])smem;         // 64x65 fp32
  const int c0 = bx*64, r0 = by*64;
  const int tid = threadIdx.x;
  const int cl = tid & 63, rlB = tid >> 6;
  #pragma unroll
  for (int p = 0; p < 16; ++p) {
    const int rl = rlB + p*4;
    const int r = r0 + rl, c = c0 + cl;
    t[rl][cl] = (r < R && c < C) ? in[(size_t)r*C + c] : 0.f;
  }
  __syncthreads();
  #pragma unroll
  for (int p = 0; p < 4; ++p) {
    const int c = p*16 + (tid >> 4);
    const int r4 = (tid & 15) * 4;
    unsigned int lo = (unsigned int)f2bf(t[r4+0][c]) | ((unsigned int)f2bf(t[r4+1][c]) << 16);
    unsigned int hi = (unsigned int)f2bf(t[r4+2][c]) | ((unsigned int)f2bf(t[r4+3][c]) << 16);
    *(uint2*)&out[(size_t)(c0 + c)*Rp + r0 + r4] = make_uint2(lo, hi);
  }
}

// fmap transpose: 64 channels x 49 hw of one batch b; packed 8B bf16 stores.
__device__ __forceinline__ void dev_transpose_fmap(float* smem,
    const float* __restrict__ fmap, ushort_t* __restrict__ out, int cc, int b)
{
  float* Fs = smem;   // [c_local][h], 64*49
  const int tid = threadIdx.x;
  const int c0 = cc*64;
  const float* fsrc = fmap + ((size_t)b*CENC + c0)*HW;   // 3136 floats contiguous
  for (int idx = tid; idx < 784; idx += 256)
    *(float4*)&Fs[idx*4] = *(const float4*)&fsrc[idx*4];
  __syncthreads();
  for (int idx = tid; idx < 784; idx += 256) {           // 49 h * 16 groups of 4 channels
    const int h = idx >> 4, c4 = (idx & 15) * 4;
    unsigned int lo = (unsigned int)f2bf(Fs[(c4+0)*49 + h]) | ((unsigned int)f2bf(Fs[(c4+1)*49 + h]) << 16);
    unsigned int hi = (unsigned int)f2bf(Fs[(c4+2)*49 + h]) | ((unsigned int)f2bf(Fs[(c4+3)*49 + h]) << 16);
    *(uint2*)&out[(size_t)(b*49 + h)*CENC + c0 + c4] = make_uint2(lo, hi);
  }
}

__device__ __forceinline__ void dev_sumP(float* smem,
    const float* __restrict__ proj_w, const float* __restrict__ proj_Y,
    float* __restrict__ sumP)
{
  float* colsum = smem;   // 192 floats
  const int tid = threadIdx.x;
  if (tid < 192) {
    float s = 0.f;
    for (int h = 0; h < 49; ++h) s += proj_w[h*192 + tid];
    colsum[tid] = s;
  }
  __syncthreads();
  if (tid < 64) {
    float s = 0.f;
    if (tid < 49) for (int k = 0; k < 192; ++k) s += colsum[k] * proj_Y[k*49 + tid];
    sumP[tid] = (tid < 49) ? s * 0.07216878364870323f : 0.f;
  }
}

// ================= fused prep kernel (single dispatch, max overlap) =================
__global__ __launch_bounds__(256) void prep_all(
    const float* __restrict__ fmap, const float* __restrict__ conv_w,
    const float* __restrict__ proj_w, const float* __restrict__ proj_Y,
    const float* __restrict__ fs_w, const float* __restrict__ fs_Y,
    const float* __restrict__ act_to, const float* __restrict__ act_from,
    const float* __restrict__ so3_w, const float* __restrict__ so3_D,
    float* __restrict__ wP, float* __restrict__ wSumP, float* __restrict__ wPsi2,
    ushort_t* __restrict__ psiT,
    ushort_t* __restrict__ actToT, ushort_t* __restrict__ actFromT,
    ushort_t* __restrict__ cwT, ushort_t* __restrict__ fmapT)
{
  __shared__ float smem[4352];   // 17408 B: gemm 4352, cvt64 4160, fmap 3136
  const int blk = blockIdx.x;
  const float is192 = 0.07216878364870323f;
  if (blk < 1) {
    dev_gemm_nn(smem, proj_w, proj_Y, wP, 49,49,192, 192,49,49, is192, 0, 0, 0, nullptr);
  } else if (blk < 9) {
    dev_gemm_nn(smem, so3_w, so3_D, wPsi2, 8,455,192, 192,455,455, is192, blk-1, 0, 0, nullptr);
  } else if (blk < 73) {
    // fs_w GEMM -> writes psiT (bf16, transposed, padded) directly
    dev_gemm_nn(smem, fs_w, fs_Y, nullptr, 4096,49,192, 192,49,0, is192, 0, blk-9, 1, psiT);
  } else if (blk < 585) {
    const int t = blk-73;   dev_transpose_cvt64(smem, act_to, 455, 4000, actToT, 512, 4096, t & 63, t >> 6);
  } else if (blk < 1097) {
    const int t = blk-585;  dev_transpose_cvt64(smem, act_from, 4000, 455, actFromT, 4096, 512, t & 7, t >> 3);
  } else if (blk < 1353) {
    const int t = blk-1097; dev_transpose_cvt64(smem, conv_w, 512, 2048, cwT, 512, 2048, t & 31, t >> 5);
  } else if (blk < 5449) {
    const int t = blk-1353; dev_transpose_fmap(smem, fmap, fmapT, t & 31, t >> 5);
  } else {
    dev_sumP(smem, proj_w, proj_Y, wSumP);
  }
}

// ---------- W2T GEMM (64x128 tile, 4 waves) + bpsi side-product ----------
__global__ __launch_bounds__(256) void gemm_w2t(
    const ushort_t* __restrict__ A, const ushort_t* __restrict__ B,
    const float* __restrict__ conv_b,
    ushort_t* __restrict__ Cb, float* __restrict__ bpsi)
{
  __shared__ ushort_t Alds[64*64];
  __shared__ ushort_t Blds[128*64];
  __shared__ float bred[256];
  const int tid = threadIdx.x;
  const int wv = tid >> 6, ln = tid & 63;
  const int col = ln & 15, quad = ln >> 4;
  const int m0 = blockIdx.y * 64, n0 = blockIdx.x * 128;
  const int lda = 512, ldb = 512, ldc = 2048, K = 512;
  const bool doB = (blockIdx.x == 0);
  const int br = tid & 63, bp = tid >> 6;

  const int rl = ln >> 3;
  const int gsw = (ln & 7) ^ rl;
  const ushort_t* aP[2]; const ushort_t* bP[4];
  ushort_t* aL[2]; ushort_t* bL[4];
  #pragma unroll
  for (int r = 0; r < 2; ++r) {
    const int R = wv*16 + r*8;
    aP[r] = A + (size_t)(m0 + R + rl)*lda + gsw*8;
    aL[r] = &Alds[R*64];
  }
  #pragma unroll
  for (int r = 0; r < 4; ++r) {
    const int R = wv*32 + r*8;
    bP[r] = B + (size_t)(n0 + R + rl)*ldb + gsw*8;
    bL[r] = &Blds[R*64];
  }

  f32x4 acc[4][2];
  #pragma unroll
  for (int i = 0; i < 4; ++i)
    #pragma unroll
    for (int j = 0; j < 2; ++j)
      acc[i][j] = (f32x4){0.f,0.f,0.f,0.f};
  float bacc = 0.f;

  for (int k0 = 0; k0 < K; k0 += 64) {
    #pragma unroll
    for (int r = 0; r < 2; ++r) { GLD16(aP[r], aL[r]); aP[r] += 64; }
    #pragma unroll
    for (int r = 0; r < 4; ++r) { GLD16(bP[r], bL[r]); bP[r] += 64; }
    __syncthreads();
    #pragma unroll
    for (int ks = 0; ks < 2; ++ks) {
      bf16x8 af[4], bfr[2];
      #pragma unroll
      for (int i = 0; i < 4; ++i) {
        const int row = i*16 + col;
        af[i] = *(bf16x8*)&Alds[row*64 + (((ks*4 + quad) ^ (row & 7)) << 3)];
      }
      #pragma unroll
      for (int j = 0; j < 2; ++j) {
        const int row = wv*32 + j*16 + col;
        bfr[j] = *(bf16x8*)&Blds[row*64 + (((ks*4 + quad) ^ (row & 7)) << 3)];
      }
      #pragma unroll
      for (int i = 0; i < 4; ++i)
        #pragma unroll
        for (int j = 0; j < 2; ++j)
          acc[i][j] = __builtin_amdgcn_mfma_f32_16x16x32_bf16(af[i], bfr[j], acc[i][j], 0, 0, 0);
    }
    if (doB) {
      #pragma unroll
      for (int qq = 0; qq < 2; ++qq) {
        const int q = bp*2 + qq;
        const int lo = (q ^ (br & 7)) << 3;
        #pragma unroll
        for (int e = 0; e < 8; ++e)
          bacc = fmaf(conv_b[k0 + q*8 + e], bf2f(Alds[br*64 + lo + e]), bacc);
      }
    }
    __syncthreads();
  }

  #pragma unroll
  for (int i = 0; i < 4; ++i) {
    const int mBase = m0 + i*16 + quad*4;
    #pragma unroll
    for (int j = 0; j < 2; ++j) {
      const int n = n0 + wv*32 + j*16 + col;
      #pragma unroll
      for (int r = 0; r < 4; ++r)
        Cb[(size_t)(mBase+r)*ldc + n] = f2bf(acc[i][j][r]);
    }
  }
  if (doB) {
    bred[bp*64 + br] = bacc;
    __syncthreads();
    if (tid < 64)
      bpsi[m0 + tid] = bred[tid] + bred[64+tid] + bred[128+tid] + bred[192+tid];
  }
}

// ---------- bf16 MFMA NT GEMM, 128x128 tile, 8 WAVES (512 thr), BK=64 ----------
// Wave wv: wr=wv>>2 (2 M-halves of 64), wc=wv&3 (4 N-quarters of 32).
// Each wave: 64x32 sub-tile, acc[4][2], 16 MFMA/K-step. 2 waves/SIMD latency hiding.
// Staging: each wave stages 16 rows of A and 16 of B (2+2 GLD16/lane),
// XOR-granule swizzle preserved (all wave row-bases ≡ 0 mod 8).
// mode 0: fp32 store | mode 1: relu->bf16 | mode 2: split-K fp32 partials
__global__ __launch_bounds__(512) void gemm8w_nt(
    const ushort_t* __restrict__ A, const ushort_t* __restrict__ B, void* __restrict__ Cv,
    int M, int N, int K, int lda, int ldb, int ldc,
    int mode, int kPartLen)
{
  __shared__ ushort_t Alds[128*64];   // 16 KB
  __shared__ ushort_t Blds[128*64];   // 16 KB
  const int tid = threadIdx.x;
  const int wv = tid >> 6, ln = tid & 63;
  const int col = ln & 15, quad = ln >> 4;
  const int wr = wv >> 2, wc = wv & 3;
  const int m0 = blockIdx.y * 128, n0 = blockIdx.x * 128;
  int kStart = 0, kEnd = K;
  float*    C  = (float*)Cv;
  ushort_t* Cb = (ushort_t*)Cv;
  if (mode == 2) {
    kStart = blockIdx.z * kPartLen;
    kEnd = min(K, kStart + kPartLen);
    C += (size_t)blockIdx.z * (size_t)M * (size_t)ldc;
  }

  const int rl = ln >> 3;          // row within 8-row group
  const int gsw = (ln & 7) ^ rl;   // swizzled granule to FETCH
  const ushort_t* aP[2]; const ushort_t* bP[2];
  ushort_t* aL[2]; ushort_t* bL[2];
  #pragma unroll
  for (int r = 0; r < 2; ++r) {
    const int R = wv*16 + r*8;     // wave wv stages rows [wv*16, wv*16+16)
    aP[r] = A + (size_t)(m0 + R + rl)*lda + kStart + gsw*8;
    aL[r] = &Alds[R*64];           // wave-uniform
    bP[r] = B + (size_t)(n0 + R + rl)*ldb + kStart + gsw*8;
    bL[r] = &Blds[R*64];
  }

  f32x4 acc[4][2];
  #pragma unroll
  for (int i = 0; i < 4; ++i)
    #pragma unroll
    for (int j = 0; j < 2; ++j)
      acc[i][j] = (f32x4){0.f,0.f,0.f,0.f};

  for (int k0 = kStart; k0 < kEnd; k0 += 64) {
    #pragma unroll
    for (int r = 0; r < 2; ++r) { GLD16(aP[r], aL[r]); aP[r] += 64; }
    #pragma unroll
    for (int r = 0; r < 2; ++r) { GLD16(bP[r], bL[r]); bP[r] += 64; }
    __syncthreads();
    #pragma unroll
    for (int ks = 0; ks < 2; ++ks) {
      bf16x8 af[4], bfr[2];
      #pragma unroll
      for (int i = 0; i < 4; ++i) {
        const int row = wr*64 + i*16 + col;
        af[i] = *(bf16x8*)&Alds[row*64 + (((ks*4 + quad) ^ (row & 7)) << 3)];
      }
      #pragma unroll
      for (int j = 0; j < 2; ++j) {
        const int row = wc*32 + j*16 + col;
        bfr[j] = *(bf16x8*)&Blds[row*64 + (((ks*4 + quad) ^ (row & 7)) << 3)];
      }
      #pragma unroll
      for (int i = 0; i < 4; ++i)
        #pragma unroll
        for (int j = 0; j < 2; ++j)
          acc[i][j] = __builtin_amdgcn_mfma_f32_16x16x32_bf16(af[i], bfr[j], acc[i][j], 0, 0, 0);
    }
    __syncthreads();
  }

  // epilogue: C/D layout col = lane&15 (n), row = quad*4 + reg (m)
  #pragma unroll
  for (int i = 0; i < 4; ++i) {
    const int mBase = m0 + wr*64 + i*16 + quad*4;
    #pragma unroll
    for (int j = 0; j < 2; ++j) {
      const int n = n0 + wc*32 + j*16 + col;
      if (mode == 1) {
        #pragma unroll
        for (int r = 0; r < 4; ++r)
          Cb[(size_t)(mBase+r)*ldc + n] = f2bf(fmaxf(acc[i][j][r], 0.f));
      } else {
        #pragma unroll
        for (int r = 0; r < 4; ++r)
          C[(size_t)(mBase+r)*ldc + n] = acc[i][j][r];
      }
    }
  }
}

// ---------- gather_y: P-contraction + block-diag gather + rank-1 bias + 1/sqrt(512) ----------
__global__ __launch_bounds__(256) void gather_y(
    const float* __restrict__ T, const float* __restrict__ P,
    const float* __restrict__ sumP, const float* __restrict__ bpsi,
    ushort_t* __restrict__ y)
{
  __shared__ float Tg[49*64];
  __shared__ float Pl[49*49];
  __shared__ float sPl[49];
  __shared__ float bps[64];
  const int tid = threadIdx.x;
  const int g = blockIdx.x & 7, b = blockIdx.x >> 3;
  for (int idx = tid; idx < 49*64; idx += 256) {
    const int h = idx >> 6, c = idx & 63;
    Tg[idx] = T[(size_t)(b*49 + h)*512 + g*64 + c];
  }
  for (int idx = tid; idx < 2401; idx += 256) Pl[idx] = P[idx];
  if (tid < 49) sPl[tid] = sumP[tid];
  if (tid < 64) bps[tid] = bpsi[g*64 + tid];
  __syncthreads();
  #pragma unroll
  for (int rr = 0; rr < 2; ++rr) {
    const int j = tid + rr*256;
    float v = 0.f;
    if (j < SO3D) {
      int l;
      if (j < 1) l = 0; else if (j < 10) l = 1; else if (j < 35) l = 2;
      else if (j < 84) l = 3; else if (j < 165) l = 4; else if (j < 286) l = 5; else l = 6;
      const int so = soff(l), d = 2*l+1;
      const int r = j - so;
      const int u = r / d, m = r - u*d;
      const int i = l*l + m, colT = l*l + u;
      float acc = 0.f;
      #pragma unroll 7
      for (int h = 0; h < 49; ++h)
        acc = fmaf(Pl[h*49 + i], Tg[h*64 + colT], acc);
      v = (acc + sPl[i]*bps[colT]) * 0.044194173824159216f;
    }
    y[(size_t)(b*8+g)*512 + j] = f2bf(v);
  }
}

// ---------- final so3 conv: 8-partial sum + per-l contraction + fp32 store ----------
__global__ __launch_bounds__(512) void so3_final(
    const float* __restrict__ zpart, const float* __restrict__ psi2,
    float* __restrict__ out)
{
  __shared__ float Zs[8*SO3D];
  __shared__ float P2s[8*SO3D];
  const int b = blockIdx.x, tid = threadIdx.x;
  for (int idx = tid; idx < 8*SO3D; idx += 512) {
    const int f = idx / SO3D, i = idx - f*SO3D;
    float s = 0.f;
    #pragma unroll
    for (int p = 0; p < 8; ++p)
      s += zpart[((size_t)p*1024 + (size_t)b*FHID + f)*512 + i];
    Zs[idx] = s;
    P2s[idx] = psi2[idx];
  }
  __syncthreads();
  if (tid < SO3D) {
    const int i = tid;
    int l;
    if (i < 1) l = 0; else if (i < 10) l = 1; else if (i < 35) l = 2;
    else if (i < 84) l = 3; else if (i < 165) l = 4; else if (i < 286) l = 5; else l = 6;
    const int so = soff(l), d = 2*l+1;
    const int r = i - so;
    const int v = r / d, m = r - v*d;
    float acc = 0.f;
    for (int f = 0; f < 8; ++f)
      for (int u = 0; u < d; ++u)
        acc = fmaf(Zs[f*SO3D + so + u*d + m], P2s[f*SO3D + so + u*d + v], acc);
    const float scale = rsqrtf(8.0f * (float)d);
    out[(size_t)b*SO3D + i] = acc * scale;
  }
}

extern "C" void kernel_launch(void* const* d_in, const int* in_sizes, int n_in,
                              void* d_out, int out_size, void* d_ws, size_t ws_size,
                              hipStream_t stream) {
  const float* fmap    = (const float*)d_in[0];
  const float* conv_w  = (const float*)d_in[1];
  const float* conv_b  = (const float*)d_in[2];
  const float* proj_w  = (const float*)d_in[3];
  const float* proj_Y  = (const float*)d_in[4];
  const float* fs_w    = (const float*)d_in[5];
  const float* fs_Y    = (const float*)d_in[6];
  const float* act_to  = (const float*)d_in[7];
  const float* act_from= (const float*)d_in[8];
  const float* so3_w   = (const float*)d_in[9];
  const float* so3_D   = (const float*)d_in[10];
  float* out           = (float*)d_out;

  // workspace (bytes), lifetime-packed; max ~54.8 MB (known-good size)
  char* wsb = (char*)d_ws;
  float*    wP       = (float*)(wsb + 0);           // 49x49 fp32
  float*    wSumP    = (float*)(wsb + 9728);        // 64 fp32
  float*    wPsi2    = (float*)(wsb + 9984);        // 8x455 fp32 -> 24544, pad 24576
  ushort_t* actToT   = (ushort_t*)(wsb + 24576);    // 4096x512 bf16 -> 4218880
  ushort_t* actFromT = (ushort_t*)(wsb + 4218880);  // 512x4096 bf16 -> 8413184
  ushort_t* yPad     = (ushort_t*)(wsb + 8413184);  // 1024x512 bf16 -> 9461760
  ushort_t* psiT     = (ushort_t*)(wsb + 9461760);  // 512x512 bf16 -> 9986048
  float*    bpsi     = (float*)(wsb + 9986048);     // 512 fp32 -> 9988096
  ushort_t* W2T      = (ushort_t*)(wsb + 9988096);  // 512x2048 bf16 -> 12085248
  ushort_t* fmapT    = (ushort_t*)(wsb + 12085248); // 6272x2048 bf16 -> 37775360 (dead after T gemm)
  ushort_t* cwT      = (ushort_t*)(wsb + 39872512); // 2048x512 bf16 -> 41969664 (dead after W2T gemm)
  float*    Tbuf     = (float*)(wsb + 41969664);    // 6272x512 fp32 -> 54814720
  // aliases into dead fmapT region:
  ushort_t* gBuf     = (ushort_t*)(wsb + 12085248); // 1024x4096 bf16 -> 20473856
  float*    zPart    = (float*)(wsb + 20473856);    // 8x1024x512 fp32 -> 37251072

  // 1) ALL independent prep in one dispatch; fs_w GEMM emits psiT directly
  prep_all<<<dim3(5450), 256, 0, stream>>>(
      fmap, conv_w, proj_w, proj_Y, fs_w, fs_Y, act_to, act_from, so3_w, so3_D,
      wP, wSumP, wPsi2, psiT, actToT, actFromT, cwT, fmapT);
  // 2) W2T[gi][c] = psiT @ cwT^T (M=512,N=2048,K=512) bf16; bx==0 also emits bpsi
  gemm_w2t<<<dim3(16,8), 256, 0, stream>>>(psiT, cwT, conv_b, W2T, bpsi);
  // 3) T[(b,h)][gi] = fmapT @ W2T^T  (M=6272, N=512, K=2048), fp32, 8-wave 128^2
  gemm8w_nt<<<dim3(4,49), 512, 0, stream>>>(fmapT, W2T, Tbuf,
      6272, 512, 2048, 2048, 2048, 512, 0, 0);
  // 4) yPad = P-contraction + block-diag gather + rank-1 bias + 1/sqrt(512)
  gather_y<<<dim3(1024), 256, 0, stream>>>(Tbuf, wP, wSumP, bpsi, yPad);
  // 5) g = relu(yPad @ actToT^T) bf16   (M=1024, N=4096, K=512), 8-wave 128^2
  gemm8w_nt<<<dim3(32,8), 512, 0, stream>>>(yPad, actToT, gBuf,
      1024, 4096, 512, 512, 512, 4096, 1, 0);
  // 6) zPart = gBuf @ actFromT^T, split-K=8  (M=1024, N=512, K=4096), 8-wave 128^2
  gemm8w_nt<<<dim3(4,8,8), 512, 0, stream>>>(gBuf, actFromT, zPart,
      1024, 512, 4096, 4096, 4096, 512, 2, 512);
  // 7) final contraction + fp32 store
  so3_final<<<dim3(128), 512, 0, stream>>>(zPart, wPsi2, out);
}

// Round 5
// 222.907 us; speedup vs baseline: 1.1177x; 1.0314x over previous
//
#include <hip/hip_runtime.h>
#include <hip/hip_bf16.h>

#define NB    128
#define CENC  2048
#define FIN   512
#define FHID  8
#define S2D   49
#define SO3D  455
#define HW    49

typedef unsigned short ushort_t;
typedef __bf16 bf16x8 __attribute__((ext_vector_type(8)));
typedef float  f32x4  __attribute__((ext_vector_type(4)));

// async global->LDS, 16B per lane; LDS dest = wave-uniform base + lane*16
#define GLD16(gp, lp) __builtin_amdgcn_global_load_lds( \
    (__attribute__((address_space(1))) const unsigned int*)(gp), \
    (__attribute__((address_space(3))) unsigned int*)(lp), 16, 0, 0)

__device__ __forceinline__ int soff(int l) { return l*(4*l*l-1)/3; }  // sum_{l'<l}(2l'+1)^2

__device__ __forceinline__ ushort_t f2bf(float x) {
  __hip_bfloat16 h = __float2bfloat16(x);
  return *reinterpret_cast<ushort_t*>(&h);
}
__device__ __forceinline__ float bf2f(ushort_t u) {
  __hip_bfloat16 h = *reinterpret_cast<__hip_bfloat16*>(&u);
  return __bfloat162float(h);
}

// ================= device building blocks for the fused prep kernel =================

// cmode 0: C store fp32*alpha. cmode 1: psiT store — psiTout[(g*64+n)*512 + f] = bf16,
// f=m>>3, g=m&7, zero-padded for n in [49,64).
__device__ __forceinline__ void dev_gemm_nn(float* smem,
    const float* __restrict__ A, const float* __restrict__ B, float* __restrict__ C,
    int M, int N, int K, int lda, int ldb, int ldc, float alpha, int bx, int by,
    int cmode, ushort_t* __restrict__ psiTout)
{
  float* As = smem;
  float* Bs = smem + 32*68;
  const int tid = threadIdx.x;
  const int tx = tid & 15, ty = tid >> 4;
  const int n0 = bx * 64, m0 = by * 64;
  float acc[4][4] = {};
  for (int k0 = 0; k0 < K; k0 += 32) {
    {
      const int kk = tid & 31, mmB = tid >> 5;
      #pragma unroll
      for (int j = 0; j < 8; ++j) {
        const int mm = mmB + 8*j;
        const int m = m0 + mm, k = k0 + kk;
        As[kk*68 + mm] = (m < M && k < K) ? A[(size_t)m*lda + k] : 0.f;
      }
    }
    {
      const int nn = tid & 63, kkB = tid >> 6;
      #pragma unroll
      for (int j = 0; j < 8; ++j) {
        const int kk = kkB + 4*j;
        const int n = n0 + nn, k = k0 + kk;
        Bs[kk*68 + nn] = (n < N && k < K) ? B[(size_t)k*ldb + n] : 0.f;
      }
    }
    __syncthreads();
    #pragma unroll
    for (int kk = 0; kk < 32; ++kk) {
      const float4 a4 = *(const float4*)&As[kk*68 + ty*4];
      const float4 b4 = *(const float4*)&Bs[kk*68 + tx*4];
      const float av[4] = {a4.x,a4.y,a4.z,a4.w};
      const float bv[4] = {b4.x,b4.y,b4.z,b4.w};
      #pragma unroll
      for (int i = 0; i < 4; ++i)
        #pragma unroll
        for (int j = 0; j < 4; ++j)
          acc[i][j] = fmaf(av[i], bv[j], acc[i][j]);
    }
    __syncthreads();
  }
  if (cmode == 1) {
    #pragma unroll
    for (int i = 0; i < 4; ++i) {
      const int m = m0 + ty*4 + i;          // m = f*8+g, always < 4096 here
      const int f = m >> 3, g = m & 7;
      #pragma unroll
      for (int j = 0; j < 4; ++j) {
        const int n = tx*4 + j;             // 0..63 — covers full pad range
        psiTout[(size_t)(g*64 + n)*512 + f] = (n < 49) ? f2bf(acc[i][j]*alpha) : (ushort_t)0;
      }
    }
    return;
  }
  #pragma unroll
  for (int i = 0; i < 4; ++i) {
    const int m = m0 + ty*4 + i;
    if (m >= M) continue;
    #pragma unroll
    for (int j = 0; j < 4; ++j) {
      const int n = n0 + tx*4 + j;
      if (n >= N) continue;
      C[(size_t)m*ldc + n] = acc[i][j] * alpha;
    }
  }
}

// 64x64 transpose + fp32->bf16 cvt, packed 8B stores.
__device__ __forceinline__ void dev_transpose_cvt64(float* smem,
    const float* __restrict__ in, int R, int C,
    ushort_t* __restrict__ out, int Rp, int Cp, int bx, int by)
{
  float (*t)[65] = (float(*)[65])smem;         // 64x65 fp32
  const int c0 = bx*64, r0 = by*64;
  const int tid = threadIdx.x;
  const int cl = tid & 63, rlB = tid >> 6;
  #pragma unroll
  for (int p = 0; p < 16; ++p) {
    const int rl = rlB + p*4;
    const int r = r0 + rl, c = c0 + cl;
    t[rl][cl] = (r < R && c < C) ? in[(size_t)r*C + c] : 0.f;
  }
  __syncthreads();
  #pragma unroll
  for (int p = 0; p < 4; ++p) {
    const int c = p*16 + (tid >> 4);
    const int r4 = (tid & 15) * 4;
    unsigned int lo = (unsigned int)f2bf(t[r4+0][c]) | ((unsigned int)f2bf(t[r4+1][c]) << 16);
    unsigned int hi = (unsigned int)f2bf(t[r4+2][c]) | ((unsigned int)f2bf(t[r4+3][c]) << 16);
    *(uint2*)&out[(size_t)(c0 + c)*Rp + r0 + r4] = make_uint2(lo, hi);
  }
}

__device__ __forceinline__ void dev_sumP(float* smem,
    const float* __restrict__ proj_w, const float* __restrict__ proj_Y,
    float* __restrict__ sumP)
{
  float* colsum = smem;   // 192 floats
  const int tid = threadIdx.x;
  if (tid < 192) {
    float s = 0.f;
    for (int h = 0; h < 49; ++h) s += proj_w[h*192 + tid];
    colsum[tid] = s;
  }
  __syncthreads();
  if (tid < 64) {
    float s = 0.f;
    if (tid < 49) for (int k = 0; k < 192; ++k) s += colsum[k] * proj_Y[k*49 + tid];
    sumP[tid] = (tid < 49) ? s * 0.07216878364870323f : 0.f;
  }
}

// ================= fused prep kernel (no fmap work anymore) =================
__global__ __launch_bounds__(256) void prep_all(
    const float* __restrict__ conv_w,
    const float* __restrict__ proj_w, const float* __restrict__ proj_Y,
    const float* __restrict__ fs_w, const float* __restrict__ fs_Y,
    const float* __restrict__ act_to, const float* __restrict__ act_from,
    const float* __restrict__ so3_w, const float* __restrict__ so3_D,
    float* __restrict__ wP, float* __restrict__ wSumP, float* __restrict__ wPsi2,
    ushort_t* __restrict__ psiT,
    ushort_t* __restrict__ actToT, ushort_t* __restrict__ actFromT,
    ushort_t* __restrict__ cwT)
{
  __shared__ float smem[4352];   // 17408 B
  const int blk = blockIdx.x;
  const float is192 = 0.07216878364870323f;
  if (blk < 1) {
    dev_gemm_nn(smem, proj_w, proj_Y, wP, 49,49,192, 192,49,49, is192, 0, 0, 0, nullptr);
  } else if (blk < 9) {
    dev_gemm_nn(smem, so3_w, so3_D, wPsi2, 8,455,192, 192,455,455, is192, blk-1, 0, 0, nullptr);
  } else if (blk < 73) {
    // fs_w GEMM -> writes psiT (bf16, transposed, padded) directly
    dev_gemm_nn(smem, fs_w, fs_Y, nullptr, 4096,49,192, 192,49,0, is192, 0, blk-9, 1, psiT);
  } else if (blk < 585) {
    const int t = blk-73;   dev_transpose_cvt64(smem, act_to, 455, 4000, actToT, 512, 4096, t & 63, t >> 6);
  } else if (blk < 1097) {
    const int t = blk-585;  dev_transpose_cvt64(smem, act_from, 4000, 455, actFromT, 4096, 512, t & 7, t >> 3);
  } else if (blk < 1353) {
    const int t = blk-1097; dev_transpose_cvt64(smem, conv_w, 512, 2048, cwT, 512, 2048, t & 31, t >> 5);
  } else {
    dev_sumP(smem, proj_w, proj_Y, wSumP);
  }
}

// ---------- xPT GEMM: xPT[b*64+i][c] = sum_hw wP[hw][i] * fmap[b][c][hw] ----------
// Fuses the old fmap transpose + the hw->i contraction (49x49) into one streaming
// MFMA kernel. Grid (b,ctile) = 128*16; block 256 thr / 4 waves; out bf16 [8192][2048].
// Rows i in [49,64) come out exactly 0 (wP pad), giving a zero-padded GEMM operand.
__global__ __launch_bounds__(256) void xpt_gemm(
    const float* __restrict__ fmap, const float* __restrict__ wP,
    ushort_t* __restrict__ xPT)
{
  __shared__ ushort_t Wl[64*64];    // wPT[i][hw] bf16, XOR-granule swizzled
  __shared__ ushort_t Fl[128*64];   // fmap [c_local][hw] bf16, swizzled
  const int tid = threadIdx.x;
  const int b = blockIdx.x >> 4, ct = blockIdx.x & 15;
  const int c0 = ct*128;
  // stage wPT (transpose of wP[hw][i]) with swizzle
  for (int idx = tid; idx < 4096; idx += 256) {
    const int i = idx >> 6, hw = idx & 63;
    const float v = (i < 49 && hw < 49) ? wP[hw*49 + i] : 0.f;
    const int pos = i*64 + ((((hw>>3) ^ (i & 7)) << 3) | (hw & 7));
    Wl[pos] = f2bf(v);
  }
  // stage fmap rows c0..c0+127 : 6272 contiguous floats, float4 loads + /49 scatter
  const float* src = fmap + ((size_t)b*CENC + c0)*HW;
  #pragma unroll
  for (int q = 0; q < 7; ++q) {
    const int f4 = q*256 + tid;
    if (f4 < 1568) {
      const float4 v = *(const float4*)&src[f4*4];
      const float vv[4] = {v.x,v.y,v.z,v.w};
      const int e0 = f4*4;
      #pragma unroll
      for (int t = 0; t < 4; ++t) {
        const int e = e0 + t;
        const int r = e/49, hw = e - r*49;
        const int pos = r*64 + ((((hw>>3) ^ (r & 7)) << 3) | (hw & 7));
        Fl[pos] = f2bf(vv[t]);
      }
    }
  }
  // zero hw-pad cols 49..63 (swizzled positions)
  for (int idx = tid; idx < 128*15; idx += 256) {
    const int r = idx/15, hw = 49 + (idx - (idx/15)*15);
    const int pos = r*64 + ((((hw>>3) ^ (r & 7)) << 3) | (hw & 7));
    Fl[pos] = 0;
  }
  __syncthreads();

  const int wv = tid >> 6, ln = tid & 63;
  const int col = ln & 15, quad = ln >> 4;
  f32x4 acc[4][2];
  #pragma unroll
  for (int i = 0; i < 4; ++i)
    #pragma unroll
    for (int j = 0; j < 2; ++j)
      acc[i][j] = (f32x4){0.f,0.f,0.f,0.f};
  #pragma unroll
  for (int ks = 0; ks < 2; ++ks) {
    bf16x8 af[4], bfr[2];
    #pragma unroll
    for (int i = 0; i < 4; ++i) {
      const int row = i*16 + col;
      af[i] = *(bf16x8*)&Wl[row*64 + (((ks*4 + quad) ^ (row & 7)) << 3)];
    }
    #pragma unroll
    for (int j = 0; j < 2; ++j) {
      const int row = wv*32 + j*16 + col;
      bfr[j] = *(bf16x8*)&Fl[row*64 + (((ks*4 + quad) ^ (row & 7)) << 3)];
    }
    #pragma unroll
    for (int i = 0; i < 4; ++i)
      #pragma unroll
      for (int j = 0; j < 2; ++j)
        acc[i][j] = __builtin_amdgcn_mfma_f32_16x16x32_bf16(af[i], bfr[j], acc[i][j], 0, 0, 0);
  }
  // D row = i (from Wl), D col = c (from Fl)
  #pragma unroll
  for (int i = 0; i < 4; ++i) {
    #pragma unroll
    for (int j = 0; j < 2; ++j) {
      #pragma unroll
      for (int r = 0; r < 4; ++r) {
        const int irow = i*16 + quad*4 + r;
        const int c = c0 + wv*32 + j*16 + col;
        xPT[(size_t)(b*64 + irow)*2048 + c] = f2bf(acc[i][j][r]);
      }
    }
  }
}

// ---------- W2T GEMM (64x128 tile, 4 waves) + bpsi side-product ----------
__global__ __launch_bounds__(256) void gemm_w2t(
    const ushort_t* __restrict__ A, const ushort_t* __restrict__ B,
    const float* __restrict__ conv_b,
    ushort_t* __restrict__ Cb, float* __restrict__ bpsi)
{
  __shared__ ushort_t Alds[64*64];
  __shared__ ushort_t Blds[128*64];
  __shared__ float bred[256];
  const int tid = threadIdx.x;
  const int wv = tid >> 6, ln = tid & 63;
  const int col = ln & 15, quad = ln >> 4;
  const int m0 = blockIdx.y * 64, n0 = blockIdx.x * 128;
  const int lda = 512, ldb = 512, ldc = 2048, K = 512;
  const bool doB = (blockIdx.x == 0);
  const int br = tid & 63, bp = tid >> 6;

  const int rl = ln >> 3;
  const int gsw = (ln & 7) ^ rl;
  const ushort_t* aP[2]; const ushort_t* bP[4];
  ushort_t* aL[2]; ushort_t* bL[4];
  #pragma unroll
  for (int r = 0; r < 2; ++r) {
    const int R = wv*16 + r*8;
    aP[r] = A + (size_t)(m0 + R + rl)*lda + gsw*8;
    aL[r] = &Alds[R*64];
  }
  #pragma unroll
  for (int r = 0; r < 4; ++r) {
    const int R = wv*32 + r*8;
    bP[r] = B + (size_t)(n0 + R + rl)*ldb + gsw*8;
    bL[r] = &Blds[R*64];
  }

  f32x4 acc[4][2];
  #pragma unroll
  for (int i = 0; i < 4; ++i)
    #pragma unroll
    for (int j = 0; j < 2; ++j)
      acc[i][j] = (f32x4){0.f,0.f,0.f,0.f};
  float bacc = 0.f;

  for (int k0 = 0; k0 < K; k0 += 64) {
    #pragma unroll
    for (int r = 0; r < 2; ++r) { GLD16(aP[r], aL[r]); aP[r] += 64; }
    #pragma unroll
    for (int r = 0; r < 4; ++r) { GLD16(bP[r], bL[r]); bP[r] += 64; }
    __syncthreads();
    #pragma unroll
    for (int ks = 0; ks < 2; ++ks) {
      bf16x8 af[4], bfr[2];
      #pragma unroll
      for (int i = 0; i < 4; ++i) {
        const int row = i*16 + col;
        af[i] = *(bf16x8*)&Alds[row*64 + (((ks*4 + quad) ^ (row & 7)) << 3)];
      }
      #pragma unroll
      for (int j = 0; j < 2; ++j) {
        const int row = wv*32 + j*16 + col;
        bfr[j] = *(bf16x8*)&Blds[row*64 + (((ks*4 + quad) ^ (row & 7)) << 3)];
      }
      #pragma unroll
      for (int i = 0; i < 4; ++i)
        #pragma unroll
        for (int j = 0; j < 2; ++j)
          acc[i][j] = __builtin_amdgcn_mfma_f32_16x16x32_bf16(af[i], bfr[j], acc[i][j], 0, 0, 0);
    }
    if (doB) {
      #pragma unroll
      for (int qq = 0; qq < 2; ++qq) {
        const int q = bp*2 + qq;
        const int lo = (q ^ (br & 7)) << 3;
        #pragma unroll
        for (int e = 0; e < 8; ++e)
          bacc = fmaf(conv_b[k0 + q*8 + e], bf2f(Alds[br*64 + lo + e]), bacc);
      }
    }
    __syncthreads();
  }

  #pragma unroll
  for (int i = 0; i < 4; ++i) {
    const int mBase = m0 + i*16 + quad*4;
    #pragma unroll
    for (int j = 0; j < 2; ++j) {
      const int n = n0 + wv*32 + j*16 + col;
      #pragma unroll
      for (int r = 0; r < 4; ++r)
        Cb[(size_t)(mBase+r)*ldc + n] = f2bf(acc[i][j][r]);
    }
  }
  if (doB) {
    bred[bp*64 + br] = bacc;
    __syncthreads();
    if (tid < 64)
      bpsi[m0 + tid] = bred[tid] + bred[64+tid] + bred[128+tid] + bred[192+tid];
  }
}

// ---------- y_blockdiag: per-l skinny GEMMs replacing T-GEMM + gather_y ----------
// For block-l: OUT[mu=(g,u)][nu=(b,m)] = sum_c W2T[g*64+l^2+u][c] * xPT[b*64+l^2+m][c]
// y[(b*8+g)*512 + soff(l)+u*d+m] = (OUT + sumP[l^2+m]*bpsi[g*64+l^2+u]) / sqrt(512).
// 64x64 tiles, 4 waves, BK=64, K=2048. Padded mu rows clamp to W2T row 511 (zeros).
// Blocks 164..171 zero yPad cols [455,512).
__global__ __launch_bounds__(256) void y_blockdiag(
    const ushort_t* __restrict__ xPT, const ushort_t* __restrict__ W2T,
    const float* __restrict__ sumP, const float* __restrict__ bpsi,
    ushort_t* __restrict__ y)
{
  const int blk = blockIdx.x, tid = threadIdx.x;
  if (blk >= 164) {   // zero-pad blocks
    const int bz = blk - 164;
    for (int idx = tid; idx < 7296; idx += 256) {
      const int row = bz*128 + idx/57, cp = 455 + (idx - (idx/57)*57);
      y[(size_t)row*512 + cp] = 0;
    }
    return;
  }
  __shared__ ushort_t Asl[64*64];   // W2T rows (mu-space)
  __shared__ ushort_t Bsl[64*64];   // xPT rows (nu-space)
  int l, lstart;
  if      (blk < 2)   { l=0; lstart=0; }
  else if (blk < 8)   { l=1; lstart=2; }
  else if (blk < 18)  { l=2; lstart=8; }
  else if (blk < 32)  { l=3; lstart=18; }
  else if (blk < 68)  { l=4; lstart=32; }
  else if (blk < 112) { l=5; lstart=68; }
  else                { l=6; lstart=112; }
  const int d = 2*l+1, ll = l*l, Ml = 8*d;
  const int local = blk - lstart, ntc = 2*d;
  const int mt = local / ntc, nt = local - mt*ntc;
  const int m0 = mt*64, n0 = nt*64;

  const int wv = tid >> 6, ln = tid & 63;
  const int col = ln & 15, quad = ln >> 4;
  const int wr = wv >> 1, wc = wv & 1;
  const int rl = ln >> 3;
  const int gsw = (ln & 7) ^ rl;

  const ushort_t* aP[2]; const ushort_t* bP[2];
  ushort_t* aL[2]; ushort_t* bL[2];
  #pragma unroll
  for (int r = 0; r < 2; ++r) {
    const int R = wv*16 + r*8;
    const int mu = m0 + R + rl;
    int grow;
    if (mu < Ml) { const int g = mu/d, u = mu - g*d; grow = g*64 + ll + u; }
    else grow = 511;                       // provably-zero W2T row
    aP[r] = W2T + (size_t)grow*2048 + gsw*8;
    aL[r] = &Asl[R*64];
    const int nu = n0 + R + rl;
    const int bb = nu/d, m = nu - bb*d;
    bP[r] = xPT + (size_t)(bb*64 + ll + m)*2048 + gsw*8;
    bL[r] = &Bsl[R*64];
  }

  f32x4 acc[2][2];
  #pragma unroll
  for (int i = 0; i < 2; ++i)
    #pragma unroll
    for (int j = 0; j < 2; ++j)
      acc[i][j] = (f32x4){0.f,0.f,0.f,0.f};

  for (int k0 = 0; k0 < 2048; k0 += 64) {
    #pragma unroll
    for (int r = 0; r < 2; ++r) { GLD16(aP[r], aL[r]); aP[r] += 64; }
    #pragma unroll
    for (int r = 0; r < 2; ++r) { GLD16(bP[r], bL[r]); bP[r] += 64; }
    __syncthreads();
    #pragma unroll
    for (int ks = 0; ks < 2; ++ks) {
      bf16x8 af[2], bfr[2];
      #pragma unroll
      for (int i = 0; i < 2; ++i) {
        const int row = wr*32 + i*16 + col;
        af[i] = *(bf16x8*)&Asl[row*64 + (((ks*4 + quad) ^ (row & 7)) << 3)];
      }
      #pragma unroll
      for (int j = 0; j < 2; ++j) {
        const int row = wc*32 + j*16 + col;
        bfr[j] = *(bf16x8*)&Bsl[row*64 + (((ks*4 + quad) ^ (row & 7)) << 3)];
      }
      #pragma unroll
      for (int i = 0; i < 2; ++i)
        #pragma unroll
        for (int j = 0; j < 2; ++j)
          acc[i][j] = __builtin_amdgcn_mfma_f32_16x16x32_bf16(af[i], bfr[j], acc[i][j], 0, 0, 0);
    }
    __syncthreads();
  }

  const float isq512 = 0.044194173824159216f;
  const int sol = soff(l);
  #pragma unroll
  for (int i = 0; i < 2; ++i) {
    #pragma unroll
    for (int j = 0; j < 2; ++j) {
      #pragma unroll
      for (int r = 0; r < 4; ++r) {
        const int mu = m0 + wr*32 + i*16 + quad*4 + r;
        if (mu >= Ml) continue;
        const int nu = n0 + wc*32 + j*16 + col;
        const int g = mu/d, u = mu - g*d;
        const int bb = nu/d, m = nu - bb*d;
        const float v = (acc[i][j][r] + sumP[ll+m]*bpsi[g*64 + ll + u]) * isq512;
        y[(size_t)(bb*8 + g)*512 + sol + u*d + m] = f2bf(v);
      }
    }
  }
}

// ---------- bf16 MFMA NT GEMM, 128x128 tile, 8 waves (512 thr), BK=64 ----------
// mode 1: relu->bf16 | mode 2: split-K fp32 partials
__global__ __launch_bounds__(512) void gemm8w_nt(
    const ushort_t* __restrict__ A, const ushort_t* __restrict__ B, void* __restrict__ Cv,
    int M, int N, int K, int lda, int ldb, int ldc,
    int mode, int kPartLen)
{
  __shared__ ushort_t Alds[128*64];   // 16 KB
  __shared__ ushort_t Blds[128*64];   // 16 KB
  const int tid = threadIdx.x;
  const int wv = tid >> 6, ln = tid & 63;
  const int col = ln & 15, quad = ln >> 4;
  const int wr = wv >> 2, wc = wv & 3;
  const int m0 = blockIdx.y * 128, n0 = blockIdx.x * 128;
  int kStart = 0, kEnd = K;
  float*    C  = (float*)Cv;
  ushort_t* Cb = (ushort_t*)Cv;
  if (mode == 2) {
    kStart = blockIdx.z * kPartLen;
    kEnd = min(K, kStart + kPartLen);
    C += (size_t)blockIdx.z * (size_t)M * (size_t)ldc;
  }

  const int rl = ln >> 3;
  const int gsw = (ln & 7) ^ rl;
  const ushort_t* aP[2]; const ushort_t* bP[2];
  ushort_t* aL[2]; ushort_t* bL[2];
  #pragma unroll
  for (int r = 0; r < 2; ++r) {
    const int R = wv*16 + r*8;
    aP[r] = A + (size_t)(m0 + R + rl)*lda + kStart + gsw*8;
    aL[r] = &Alds[R*64];
    bP[r] = B + (size_t)(n0 + R + rl)*ldb + kStart + gsw*8;
    bL[r] = &Blds[R*64];
  }

  f32x4 acc[4][2];
  #pragma unroll
  for (int i = 0; i < 4; ++i)
    #pragma unroll
    for (int j = 0; j < 2; ++j)
      acc[i][j] = (f32x4){0.f,0.f,0.f,0.f};

  for (int k0 = kStart; k0 < kEnd; k0 += 64) {
    #pragma unroll
    for (int r = 0; r < 2; ++r) { GLD16(aP[r], aL[r]); aP[r] += 64; }
    #pragma unroll
    for (int r = 0; r < 2; ++r) { GLD16(bP[r], bL[r]); bP[r] += 64; }
    __syncthreads();
    #pragma unroll
    for (int ks = 0; ks < 2; ++ks) {
      bf16x8 af[4], bfr[2];
      #pragma unroll
      for (int i = 0; i < 4; ++i) {
        const int row = wr*64 + i*16 + col;
        af[i] = *(bf16x8*)&Alds[row*64 + (((ks*4 + quad) ^ (row & 7)) << 3)];
      }
      #pragma unroll
      for (int j = 0; j < 2; ++j) {
        const int row = wc*32 + j*16 + col;
        bfr[j] = *(bf16x8*)&Blds[row*64 + (((ks*4 + quad) ^ (row & 7)) << 3)];
      }
      #pragma unroll
      for (int i = 0; i < 4; ++i)
        #pragma unroll
        for (int j = 0; j < 2; ++j)
          acc[i][j] = __builtin_amdgcn_mfma_f32_16x16x32_bf16(af[i], bfr[j], acc[i][j], 0, 0, 0);
    }
    __syncthreads();
  }

  #pragma unroll
  for (int i = 0; i < 4; ++i) {
    const int mBase = m0 + wr*64 + i*16 + quad*4;
    #pragma unroll
    for (int j = 0; j < 2; ++j) {
      const int n = n0 + wc*32 + j*16 + col;
      if (mode == 1) {
        #pragma unroll
        for (int r = 0; r < 4; ++r)
          Cb[(size_t)(mBase+r)*ldc + n] = f2bf(fmaxf(acc[i][j][r], 0.f));
      } else {
        #pragma unroll
        for (int r = 0; r < 4; ++r)
          C[(size_t)(mBase+r)*ldc + n] = acc[i][j][r];
      }
    }
  }
}

// ---------- final so3 conv: 8-partial sum + per-l contraction + fp32 store ----------
__global__ __launch_bounds__(512) void so3_final(
    const float* __restrict__ zpart, const float* __restrict__ psi2,
    float* __restrict__ out)
{
  __shared__ float Zs[8*SO3D];
  __shared__ float P2s[8*SO3D];
  const int b = blockIdx.x, tid = threadIdx.x;
  for (int idx = tid; idx < 8*SO3D; idx += 512) {
    const int f = idx / SO3D, i = idx - f*SO3D;
    float s = 0.f;
    #pragma unroll
    for (int p = 0; p < 8; ++p)
      s += zpart[((size_t)p*1024 + (size_t)b*FHID + f)*512 + i];
    Zs[idx] = s;
    P2s[idx] = psi2[idx];
  }
  __syncthreads();
  if (tid < SO3D) {
    const int i = tid;
    int l;
    if (i < 1) l = 0; else if (i < 10) l = 1; else if (i < 35) l = 2;
    else if (i < 84) l = 3; else if (i < 165) l = 4; else if (i < 286) l = 5; else l = 6;
    const int so = soff(l), d = 2*l+1;
    const int r = i - so;
    const int v = r / d, m = r - v*d;
    float acc = 0.f;
    for (int f = 0; f < 8; ++f)
      for (int u = 0; u < d; ++u)
        acc = fmaf(Zs[f*SO3D + so + u*d + m], P2s[f*SO3D + so + u*d + v], acc);
    const float scale = rsqrtf(8.0f * (float)d);
    out[(size_t)b*SO3D + i] = acc * scale;
  }
}

extern "C" void kernel_launch(void* const* d_in, const int* in_sizes, int n_in,
                              void* d_out, int out_size, void* d_ws, size_t ws_size,
                              hipStream_t stream) {
  const float* fmap    = (const float*)d_in[0];
  const float* conv_w  = (const float*)d_in[1];
  const float* conv_b  = (const float*)d_in[2];
  const float* proj_w  = (const float*)d_in[3];
  const float* proj_Y  = (const float*)d_in[4];
  const float* fs_w    = (const float*)d_in[5];
  const float* fs_Y    = (const float*)d_in[6];
  const float* act_to  = (const float*)d_in[7];
  const float* act_from= (const float*)d_in[8];
  const float* so3_w   = (const float*)d_in[9];
  const float* so3_D   = (const float*)d_in[10];
  float* out           = (float*)d_out;

  // workspace (bytes), lifetime-packed; max ~47.7 MB (< 54.8 MB known-good)
  char* wsb = (char*)d_ws;
  float*    wP       = (float*)(wsb + 0);           // 49x49 fp32
  float*    wSumP    = (float*)(wsb + 9728);        // 64 fp32
  float*    wPsi2    = (float*)(wsb + 9984);        // 8x455 fp32 -> 24544, pad 24576
  ushort_t* actToT   = (ushort_t*)(wsb + 24576);    // 4096x512 bf16 -> 4218880
  ushort_t* actFromT = (ushort_t*)(wsb + 4218880);  // 512x4096 bf16 -> 8413184
  ushort_t* yPad     = (ushort_t*)(wsb + 8413184);  // 1024x512 bf16 -> 9461760
  ushort_t* psiT     = (ushort_t*)(wsb + 9461760);  // 512x512 bf16 -> 9986048
  float*    bpsi     = (float*)(wsb + 9986048);     // 512 fp32 -> 9988096
  ushort_t* W2T      = (ushort_t*)(wsb + 9988096);  // 512x2048 bf16 -> 12085248
  ushort_t* xPT      = (ushort_t*)(wsb + 12085248); // 8192x2048 bf16 -> 45639680 (dead after y_blockdiag)
  ushort_t* cwT      = (ushort_t*)(wsb + 45639680); // 2048x512 bf16 -> 47736832 (dead after W2T gemm)
  // aliases into dead xPT region:
  ushort_t* gBuf     = (ushort_t*)(wsb + 12085248); // 1024x4096 bf16 -> 20473856
  float*    zPart    = (float*)(wsb + 20473856);    // 8x1024x512 fp32 -> 37251072

  // 1) independent prep (no fmap work): small GEMMs + 3 weight transposes + sumP
  prep_all<<<dim3(1354), 256, 0, stream>>>(
      conv_w, proj_w, proj_Y, fs_w, fs_Y, act_to, act_from, so3_w, so3_D,
      wP, wSumP, wPsi2, psiT, actToT, actFromT, cwT);
  // 2) xPT[b*64+i][c] = fmap x wP  (fuses fmap transpose + hw-contraction)
  xpt_gemm<<<dim3(2048), 256, 0, stream>>>(fmap, wP, xPT);
  // 3) W2T[gi][c] = psiT @ cwT^T (M=512,N=2048,K=512) bf16; bx==0 also emits bpsi
  gemm_w2t<<<dim3(16,8), 256, 0, stream>>>(psiT, cwT, conv_b, W2T, bpsi);
  // 4) y = block-diag contraction of xPT with W2T + rank-1 bias (replaces T-GEMM+gather)
  y_blockdiag<<<dim3(172), 256, 0, stream>>>(xPT, W2T, wSumP, bpsi, yPad);
  // 5) g = relu(yPad @ actToT^T) bf16   (M=1024, N=4096, K=512), 8-wave 128^2
  gemm8w_nt<<<dim3(32,8), 512, 0, stream>>>(yPad, actToT, gBuf,
      1024, 4096, 512, 512, 512, 4096, 1, 0);
  // 6) zPart = gBuf @ actFromT^T, split-K=8  (M=1024, N=512, K=4096), 8-wave 128^2
  gemm8w_nt<<<dim3(4,8,8), 512, 0, stream>>>(gBuf, actFromT, zPart,
      1024, 512, 4096, 4096, 4096, 512, 2, 512);
  // 7) final contraction + fp32 store
  so3_final<<<dim3(128), 512, 0, stream>>>(zPart, wPsi2, out);
}

// Round 6
// 208.789 us; speedup vs baseline: 1.1933x; 1.0676x over previous
//
#include <hip/hip_runtime.h>
#include <hip/hip_bf16.h>

#define NB    128
#define CENC  2048
#define FIN   512
#define FHID  8
#define S2D   49
#define SO3D  455
#define HW    49

typedef unsigned short ushort_t;
typedef __bf16 bf16x8 __attribute__((ext_vector_type(8)));
typedef float  f32x4  __attribute__((ext_vector_type(4)));

// async global->LDS, 16B per lane; LDS dest = wave-uniform base + lane*16
#define GLD16(gp, lp) __builtin_amdgcn_global_load_lds( \
    (__attribute__((address_space(1))) const unsigned int*)(gp), \
    (__attribute__((address_space(3))) unsigned int*)(lp), 16, 0, 0)

__device__ __forceinline__ int soff(int l) { return l*(4*l*l-1)/3; }  // sum_{l'<l}(2l'+1)^2

__device__ __forceinline__ ushort_t f2bf(float x) {
  __hip_bfloat16 h = __float2bfloat16(x);
  return *reinterpret_cast<ushort_t*>(&h);
}
__device__ __forceinline__ float bf2f(ushort_t u) {
  __hip_bfloat16 h = *reinterpret_cast<__hip_bfloat16*>(&u);
  return __bfloat162float(h);
}

// ================= device building blocks for the fused prep kernel =================

// cmode 0: C store fp32*alpha.
// cmode 1: psiT store — psiTout[(g*64+n)*512 + f] = bf16, f=m>>3, g=m&7, zero-pad n in [49,64).
// cmode 2: wPT64 store — full 64x64 bf16, pre-swizzled, row=n (i), col=m (hw), zero-padded.
__device__ __forceinline__ void dev_gemm_nn(float* smem,
    const float* __restrict__ A, const float* __restrict__ B, float* __restrict__ C,
    int M, int N, int K, int lda, int ldb, int ldc, float alpha, int bx, int by,
    int cmode, ushort_t* __restrict__ uOut)
{
  float* As = smem;
  float* Bs = smem + 32*68;
  const int tid = threadIdx.x;
  const int tx = tid & 15, ty = tid >> 4;
  const int n0 = bx * 64, m0 = by * 64;
  float acc[4][4] = {};
  for (int k0 = 0; k0 < K; k0 += 32) {
    {
      const int kk = tid & 31, mmB = tid >> 5;
      #pragma unroll
      for (int j = 0; j < 8; ++j) {
        const int mm = mmB + 8*j;
        const int m = m0 + mm, k = k0 + kk;
        As[kk*68 + mm] = (m < M && k < K) ? A[(size_t)m*lda + k] : 0.f;
      }
    }
    {
      const int nn = tid & 63, kkB = tid >> 6;
      #pragma unroll
      for (int j = 0; j < 8; ++j) {
        const int kk = kkB + 4*j;
        const int n = n0 + nn, k = k0 + kk;
        Bs[kk*68 + nn] = (n < N && k < K) ? B[(size_t)k*ldb + n] : 0.f;
      }
    }
    __syncthreads();
    #pragma unroll
    for (int kk = 0; kk < 32; ++kk) {
      const float4 a4 = *(const float4*)&As[kk*68 + ty*4];
      const float4 b4 = *(const float4*)&Bs[kk*68 + tx*4];
      const float av[4] = {a4.x,a4.y,a4.z,a4.w};
      const float bv[4] = {b4.x,b4.y,b4.z,b4.w};
      #pragma unroll
      for (int i = 0; i < 4; ++i)
        #pragma unroll
        for (int j = 0; j < 4; ++j)
          acc[i][j] = fmaf(av[i], bv[j], acc[i][j]);
    }
    __syncthreads();
  }
  if (cmode == 1) {
    #pragma unroll
    for (int i = 0; i < 4; ++i) {
      const int m = m0 + ty*4 + i;          // m = f*8+g
      const int f = m >> 3, g = m & 7;
      #pragma unroll
      for (int j = 0; j < 4; ++j) {
        const int n = tx*4 + j;
        uOut[(size_t)(g*64 + n)*512 + f] = (n < 49) ? f2bf(acc[i][j]*alpha) : (ushort_t)0;
      }
    }
    return;
  }
  if (cmode == 2) {
    // wPT64[i=n][hw=m] bf16, XOR-granule swizzled, zero-padded to 64x64
    #pragma unroll
    for (int i = 0; i < 4; ++i) {
      const int m = ty*4 + i;               // hw (0..63)
      #pragma unroll
      for (int j = 0; j < 4; ++j) {
        const int n = tx*4 + j;             // i-col (0..63)
        const float v = (m < 49 && n < 49) ? acc[i][j]*alpha : 0.f;
        uOut[n*64 + ((((m>>3) ^ (n&7)) << 3) | (m&7))] = f2bf(v);
      }
    }
    return;
  }
  #pragma unroll
  for (int i = 0; i < 4; ++i) {
    const int m = m0 + ty*4 + i;
    if (m >= M) continue;
    #pragma unroll
    for (int j = 0; j < 4; ++j) {
      const int n = n0 + tx*4 + j;
      if (n >= N) continue;
      C[(size_t)m*ldc + n] = acc[i][j] * alpha;
    }
  }
}

// 64x64 transpose + fp32->bf16 cvt, packed 8B stores.
__device__ __forceinline__ void dev_transpose_cvt64(float* smem,
    const float* __restrict__ in, int R, int C,
    ushort_t* __restrict__ out, int Rp, int Cp, int bx, int by)
{
  float (*t)[65] = (float(*)[65])smem;         // 64x65 fp32
  const int c0 = bx*64, r0 = by*64;
  const int tid = threadIdx.x;
  const int cl = tid & 63, rlB = tid >> 6;
  #pragma unroll
  for (int p = 0; p < 16; ++p) {
    const int rl = rlB + p*4;
    const int r = r0 + rl, c = c0 + cl;
    t[rl][cl] = (r < R && c < C) ? in[(size_t)r*C + c] : 0.f;
  }
  __syncthreads();
  #pragma unroll
  for (int p = 0; p < 4; ++p) {
    const int c = p*16 + (tid >> 4);
    const int r4 = (tid & 15) * 4;
    unsigned int lo = (unsigned int)f2bf(t[r4+0][c]) | ((unsigned int)f2bf(t[r4+1][c]) << 16);
    unsigned int hi = (unsigned int)f2bf(t[r4+2][c]) | ((unsigned int)f2bf(t[r4+3][c]) << 16);
    *(uint2*)&out[(size_t)(c0 + c)*Rp + r0 + r4] = make_uint2(lo, hi);
  }
}

__device__ __forceinline__ void dev_sumP(float* smem,
    const float* __restrict__ proj_w, const float* __restrict__ proj_Y,
    float* __restrict__ sumP)
{
  float* colsum = smem;   // 192 floats
  const int tid = threadIdx.x;
  if (tid < 192) {
    float s = 0.f;
    for (int h = 0; h < 49; ++h) s += proj_w[h*192 + tid];
    colsum[tid] = s;
  }
  __syncthreads();
  if (tid < 64) {
    float s = 0.f;
    if (tid < 49) for (int k = 0; k < 192; ++k) s += colsum[k] * proj_Y[k*49 + tid];
    sumP[tid] = (tid < 49) ? s * 0.07216878364870323f : 0.f;
  }
}

// ================= fused prep kernel =================
__global__ __launch_bounds__(256) void prep_all(
    const float* __restrict__ conv_w,
    const float* __restrict__ proj_w, const float* __restrict__ proj_Y,
    const float* __restrict__ fs_w, const float* __restrict__ fs_Y,
    const float* __restrict__ act_to, const float* __restrict__ act_from,
    const float* __restrict__ so3_w, const float* __restrict__ so3_D,
    ushort_t* __restrict__ wPT64, float* __restrict__ wSumP, float* __restrict__ wPsi2,
    ushort_t* __restrict__ psiT,
    ushort_t* __restrict__ actToT, ushort_t* __restrict__ actFromT,
    ushort_t* __restrict__ cwT)
{
  __shared__ float smem[4352];   // 17408 B
  const int blk = blockIdx.x;
  const float is192 = 0.07216878364870323f;
  if (blk < 1) {
    // wP GEMM -> writes wPT64 (bf16, transposed, swizzled, padded) directly
    dev_gemm_nn(smem, proj_w, proj_Y, nullptr, 49,49,192, 192,49,0, is192, 0, 0, 2, wPT64);
  } else if (blk < 9) {
    dev_gemm_nn(smem, so3_w, so3_D, wPsi2, 8,455,192, 192,455,455, is192, blk-1, 0, 0, nullptr);
  } else if (blk < 73) {
    dev_gemm_nn(smem, fs_w, fs_Y, nullptr, 4096,49,192, 192,49,0, is192, 0, blk-9, 1, psiT);
  } else if (blk < 585) {
    const int t = blk-73;   dev_transpose_cvt64(smem, act_to, 455, 4000, actToT, 512, 4096, t & 63, t >> 6);
  } else if (blk < 1097) {
    const int t = blk-585;  dev_transpose_cvt64(smem, act_from, 4000, 455, actFromT, 4096, 512, t & 7, t >> 3);
  } else if (blk < 1353) {
    const int t = blk-1097; dev_transpose_cvt64(smem, conv_w, 512, 2048, cwT, 512, 2048, t & 31, t >> 5);
  } else {
    dev_sumP(smem, proj_w, proj_Y, wSumP);
  }
}

// ---------- xpt body: xPT[b*64+i][c] = sum_hw wPT64[i][hw] * fmap[b][c][hw] ----------
__device__ __forceinline__ void dev_xpt(
    ushort_t* Wl, ushort_t* Fl,
    const float* __restrict__ fmap, const ushort_t* __restrict__ wPT64,
    ushort_t* __restrict__ xPT, int blk)
{
  const int tid = threadIdx.x;
  const int wv = tid >> 6, ln = tid & 63;
  const int b = blk >> 4, ct = blk & 15;
  const int c0 = ct*128;
  // Wl: linear async copy of pre-swizzled wPT64 (8 KB): 2 GLD16 per thread
  #pragma unroll
  for (int q = 0; q < 2; ++q)
    GLD16(wPT64 + (wv*2+q)*512 + ln*8, Wl + (wv*2+q)*512);
  // Fl: fmap rows c0..c0+127 (6272 contiguous floats), div-free incremental scatter
  const float* src = fmap + ((size_t)b*CENC + c0)*HW;
  int r = (tid*4)/49, hw = tid*4 - r*49;
  #pragma unroll
  for (int q = 0; q < 7; ++q) {
    const int f4 = q*256 + tid;
    if (f4 < 1568) {
      const float4 v = *(const float4*)&src[(size_t)f4*4];
      const float vv[4] = {v.x, v.y, v.z, v.w};
      int rr = r, hh = hw;
      #pragma unroll
      for (int t = 0; t < 4; ++t) {
        Fl[rr*64 + ((((hh>>3) ^ (rr&7)) << 3) | (hh&7))] = f2bf(vv[t]);
        if (++hh == 49) { hh = 0; ++rr; }
      }
    }
    r += 20; hw += 44;                 // advance e by 1024 = 20*49+44
    if (hw >= 49) { hw -= 49; ++r; }
  }
  // zero hw-pad cols 49..63 (disjoint from main-loop writes, no barrier needed)
  #pragma unroll
  for (int q = 0; q < 8; ++q) {
    const int idx = q*256 + tid;
    const int rr = idx >> 4, j = idx & 15;
    if (j) {
      const int hh = 48 + j;
      Fl[rr*64 + ((((hh>>3) ^ (rr&7)) << 3) | (hh&7))] = 0;
    }
  }
  __syncthreads();

  const int col = ln & 15, quad = ln >> 4;
  f32x4 acc[4][2];
  #pragma unroll
  for (int i = 0; i < 4; ++i)
    #pragma unroll
    for (int j = 0; j < 2; ++j)
      acc[i][j] = (f32x4){0.f,0.f,0.f,0.f};
  #pragma unroll
  for (int ks = 0; ks < 2; ++ks) {
    bf16x8 af[4], bfr[2];
    #pragma unroll
    for (int i = 0; i < 4; ++i) {
      const int row = i*16 + col;
      af[i] = *(bf16x8*)&Wl[row*64 + (((ks*4 + quad) ^ (row & 7)) << 3)];
    }
    #pragma unroll
    for (int j = 0; j < 2; ++j) {
      const int row = wv*32 + j*16 + col;
      bfr[j] = *(bf16x8*)&Fl[row*64 + (((ks*4 + quad) ^ (row & 7)) << 3)];
    }
    #pragma unroll
    for (int i = 0; i < 4; ++i)
      #pragma unroll
      for (int j = 0; j < 2; ++j)
        acc[i][j] = __builtin_amdgcn_mfma_f32_16x16x32_bf16(af[i], bfr[j], acc[i][j], 0, 0, 0);
  }
  #pragma unroll
  for (int i = 0; i < 4; ++i) {
    #pragma unroll
    for (int j = 0; j < 2; ++j) {
      #pragma unroll
      for (int r2 = 0; r2 < 4; ++r2) {
        const int irow = i*16 + quad*4 + r2;
        const int c = c0 + wv*32 + j*16 + col;
        xPT[(size_t)(b*64 + irow)*2048 + c] = f2bf(acc[i][j][r2]);
      }
    }
  }
}

// ---------- w2t body (64x128 tile, 4 waves) + bpsi side-product ----------
__device__ __forceinline__ void dev_w2t(
    ushort_t* Alds, ushort_t* Blds, float* bred,
    const ushort_t* __restrict__ A, const ushort_t* __restrict__ B,
    const float* __restrict__ conv_b,
    ushort_t* __restrict__ Cb, float* __restrict__ bpsi, int bx, int by)
{
  const int tid = threadIdx.x;
  const int wv = tid >> 6, ln = tid & 63;
  const int col = ln & 15, quad = ln >> 4;
  const int m0 = by * 64, n0 = bx * 128;
  const int lda = 512, ldb = 512, ldc = 2048, K = 512;
  const bool doB = (bx == 0);
  const int br = tid & 63, bp = tid >> 6;

  const int rl = ln >> 3;
  const int gsw = (ln & 7) ^ rl;
  const ushort_t* aP[2]; const ushort_t* bP[4];
  ushort_t* aL[2]; ushort_t* bL[4];
  #pragma unroll
  for (int r = 0; r < 2; ++r) {
    const int R = wv*16 + r*8;
    aP[r] = A + (size_t)(m0 + R + rl)*lda + gsw*8;
    aL[r] = &Alds[R*64];
  }
  #pragma unroll
  for (int r = 0; r < 4; ++r) {
    const int R = wv*32 + r*8;
    bP[r] = B + (size_t)(n0 + R + rl)*ldb + gsw*8;
    bL[r] = &Blds[R*64];
  }

  f32x4 acc[4][2];
  #pragma unroll
  for (int i = 0; i < 4; ++i)
    #pragma unroll
    for (int j = 0; j < 2; ++j)
      acc[i][j] = (f32x4){0.f,0.f,0.f,0.f};
  float bacc = 0.f;

  for (int k0 = 0; k0 < K; k0 += 64) {
    #pragma unroll
    for (int r = 0; r < 2; ++r) { GLD16(aP[r], aL[r]); aP[r] += 64; }
    #pragma unroll
    for (int r = 0; r < 4; ++r) { GLD16(bP[r], bL[r]); bP[r] += 64; }
    __syncthreads();
    #pragma unroll
    for (int ks = 0; ks < 2; ++ks) {
      bf16x8 af[4], bfr[2];
      #pragma unroll
      for (int i = 0; i < 4; ++i) {
        const int row = i*16 + col;
        af[i] = *(bf16x8*)&Alds[row*64 + (((ks*4 + quad) ^ (row & 7)) << 3)];
      }
      #pragma unroll
      for (int j = 0; j < 2; ++j) {
        const int row = wv*32 + j*16 + col;
        bfr[j] = *(bf16x8*)&Blds[row*64 + (((ks*4 + quad) ^ (row & 7)) << 3)];
      }
      #pragma unroll
      for (int i = 0; i < 4; ++i)
        #pragma unroll
        for (int j = 0; j < 2; ++j)
          acc[i][j] = __builtin_amdgcn_mfma_f32_16x16x32_bf16(af[i], bfr[j], acc[i][j], 0, 0, 0);
    }
    if (doB) {
      #pragma unroll
      for (int qq = 0; qq < 2; ++qq) {
        const int q = bp*2 + qq;
        const int lo = (q ^ (br & 7)) << 3;
        #pragma unroll
        for (int e = 0; e < 8; ++e)
          bacc = fmaf(conv_b[k0 + q*8 + e], bf2f(Alds[br*64 + lo + e]), bacc);
      }
    }
    __syncthreads();
  }

  #pragma unroll
  for (int i = 0; i < 4; ++i) {
    const int mBase = m0 + i*16 + quad*4;
    #pragma unroll
    for (int j = 0; j < 2; ++j) {
      const int n = n0 + wv*32 + j*16 + col;
      #pragma unroll
      for (int r = 0; r < 4; ++r)
        Cb[(size_t)(mBase+r)*ldc + n] = f2bf(acc[i][j][r]);
    }
  }
  if (doB) {
    bred[bp*64 + br] = bacc;
    __syncthreads();
    if (tid < 64)
      bpsi[m0 + tid] = bred[tid] + bred[64+tid] + bred[128+tid] + bred[192+tid];
  }
}

// ---------- fused mid dispatch: xpt (2048) + w2t (128) + yPad zero-pad (8) ----------
__global__ __launch_bounds__(256) void mid_fused(
    const float* __restrict__ fmap, const ushort_t* __restrict__ wPT64,
    const ushort_t* __restrict__ psiT, const ushort_t* __restrict__ cwT,
    const float* __restrict__ conv_b,
    ushort_t* __restrict__ xPT, ushort_t* __restrict__ W2T,
    float* __restrict__ bpsi, ushort_t* __restrict__ yPad)
{
  __shared__ __align__(16) ushort_t smem[12800];   // 25600 B
  const int blk = blockIdx.x;
  if (blk < 2048) {
    dev_xpt(smem, smem + 4096, fmap, wPT64, xPT, blk);
  } else if (blk < 2176) {
    const int t = blk - 2048;
    dev_w2t(smem, smem + 4096, (float*)(smem + 12288),
            psiT, cwT, conv_b, W2T, bpsi, t & 15, t >> 4);
  } else {
    const int bz = blk - 2176, tid = threadIdx.x;
    for (int idx = tid; idx < 7296; idx += 256) {
      const int row = bz*128 + idx/57, cp = 455 + (idx - (idx/57)*57);
      yPad[(size_t)row*512 + cp] = 0;
    }
  }
}

// ---------- y_blockdiag: per-l skinny GEMMs, BK=128, K=2048 ----------
// OUT[mu=(g,u)][nu=(b,m)] = sum_c W2T[g*64+l^2+u][c] * xPT[b*64+l^2+m][c]
// y[(b*8+g)*512 + soff(l)+u*d+m] = (OUT + sumP[l^2+m]*bpsi[g*64+l^2+u]) / sqrt(512).
__global__ __launch_bounds__(256) void y_blockdiag(
    const ushort_t* __restrict__ xPT, const ushort_t* __restrict__ W2T,
    const float* __restrict__ sumP, const float* __restrict__ bpsi,
    ushort_t* __restrict__ y)
{
  __shared__ __align__(16) ushort_t Asl[64*128];   // 16 KB
  __shared__ __align__(16) ushort_t Bsl[64*128];   // 16 KB
  const int blk = blockIdx.x, tid = threadIdx.x;
  int l, lstart;
  if      (blk < 2)   { l=0; lstart=0; }
  else if (blk < 8)   { l=1; lstart=2; }
  else if (blk < 18)  { l=2; lstart=8; }
  else if (blk < 32)  { l=3; lstart=18; }
  else if (blk < 68)  { l=4; lstart=32; }
  else if (blk < 112) { l=5; lstart=68; }
  else                { l=6; lstart=112; }
  const int d = 2*l+1, ll = l*l, Ml = 8*d;
  const int local = blk - lstart, ntc = 2*d;
  const int mt = local / ntc, nt = local - mt*ntc;
  const int m0 = mt*64, n0 = nt*64;

  const int wv = tid >> 6, ln = tid & 63;
  const int col = ln & 15, quad = ln >> 4;
  const int wr = wv >> 1, wc = wv & 1;
  const int rl4 = ln >> 4;         // row within 4-row GLD16 group
  const int gi = ln & 15;          // LDS granule slot

  const ushort_t* aP[4]; const ushort_t* bP[4];
  ushort_t* aL[4]; ushort_t* bL[4];
  #pragma unroll
  for (int r = 0; r < 4; ++r) {
    const int R = wv*16 + r*4;
    const int row = R + rl4;                 // 0..63
    const int gsw = gi ^ (row & 15);         // fetched granule for slot gi
    const int mu = m0 + row;
    int grow;
    if (mu < Ml) { const int g = mu/d, u = mu - g*d; grow = g*64 + ll + u; }
    else grow = 511;                          // provably-zero W2T row
    aP[r] = W2T + (size_t)grow*2048 + gsw*8;
    aL[r] = &Asl[R*128];
    const int nu = n0 + row;
    const int bb = nu/d, m = nu - bb*d;
    bP[r] = xPT + (size_t)(bb*64 + ll + m)*2048 + gsw*8;
    bL[r] = &Bsl[R*128];
  }

  f32x4 acc[2][2];
  #pragma unroll
  for (int i = 0; i < 2; ++i)
    #pragma unroll
    for (int j = 0; j < 2; ++j)
      acc[i][j] = (f32x4){0.f,0.f,0.f,0.f};

  for (int k0 = 0; k0 < 2048; k0 += 128) {
    #pragma unroll
    for (int r = 0; r < 4; ++r) { GLD16(aP[r], aL[r]); aP[r] += 128; }
    #pragma unroll
    for (int r = 0; r < 4; ++r) { GLD16(bP[r], bL[r]); bP[r] += 128; }
    __syncthreads();
    #pragma unroll
    for (int ks = 0; ks < 4; ++ks) {
      bf16x8 af[2], bfr[2];
      #pragma unroll
      for (int i = 0; i < 2; ++i) {
        const int row = wr*32 + i*16 + col;
        af[i] = *(bf16x8*)&Asl[row*128 + (((ks*4 + quad) ^ (row & 15)) << 3)];
      }
      #pragma unroll
      for (int j = 0; j < 2; ++j) {
        const int row = wc*32 + j*16 + col;
        bfr[j] = *(bf16x8*)&Bsl[row*128 + (((ks*4 + quad) ^ (row & 15)) << 3)];
      }
      #pragma unroll
      for (int i = 0; i < 2; ++i)
        #pragma unroll
        for (int j = 0; j < 2; ++j)
          acc[i][j] = __builtin_amdgcn_mfma_f32_16x16x32_bf16(af[i], bfr[j], acc[i][j], 0, 0, 0);
    }
    __syncthreads();
  }

  const float isq512 = 0.044194173824159216f;
  const int sol = soff(l);
  #pragma unroll
  for (int i = 0; i < 2; ++i) {
    #pragma unroll
    for (int j = 0; j < 2; ++j) {
      #pragma unroll
      for (int r = 0; r < 4; ++r) {
        const int mu = m0 + wr*32 + i*16 + quad*4 + r;
        if (mu >= Ml) continue;
        const int nu = n0 + wc*32 + j*16 + col;
        const int g = mu/d, u = mu - g*d;
        const int bb = nu/d, m = nu - bb*d;
        const float v = (acc[i][j][r] + sumP[ll+m]*bpsi[g*64 + ll + u]) * isq512;
        y[(size_t)(bb*8 + g)*512 + sol + u*d + m] = f2bf(v);
      }
    }
  }
}

// ---------- bf16 MFMA NT GEMM, 128x128 tile, 8 waves (512 thr), BK=64 ----------
// mode 1: relu->bf16 | mode 2: split-K fp32 partials
__global__ __launch_bounds__(512) void gemm8w_nt(
    const ushort_t* __restrict__ A, const ushort_t* __restrict__ B, void* __restrict__ Cv,
    int M, int N, int K, int lda, int ldb, int ldc,
    int mode, int kPartLen)
{
  __shared__ ushort_t Alds[128*64];   // 16 KB
  __shared__ ushort_t Blds[128*64];   // 16 KB
  const int tid = threadIdx.x;
  const int wv = tid >> 6, ln = tid & 63;
  const int col = ln & 15, quad = ln >> 4;
  const int wr = wv >> 2, wc = wv & 3;
  const int m0 = blockIdx.y * 128, n0 = blockIdx.x * 128;
  int kStart = 0, kEnd = K;
  float*    C  = (float*)Cv;
  ushort_t* Cb = (ushort_t*)Cv;
  if (mode == 2) {
    kStart = blockIdx.z * kPartLen;
    kEnd = min(K, kStart + kPartLen);
    C += (size_t)blockIdx.z * (size_t)M * (size_t)ldc;
  }

  const int rl = ln >> 3;
  const int gsw = (ln & 7) ^ rl;
  const ushort_t* aP[2]; const ushort_t* bP[2];
  ushort_t* aL[2]; ushort_t* bL[2];
  #pragma unroll
  for (int r = 0; r < 2; ++r) {
    const int R = wv*16 + r*8;
    aP[r] = A + (size_t)(m0 + R + rl)*lda + kStart + gsw*8;
    aL[r] = &Alds[R*64];
    bP[r] = B + (size_t)(n0 + R + rl)*ldb + kStart + gsw*8;
    bL[r] = &Blds[R*64];
  }

  f32x4 acc[4][2];
  #pragma unroll
  for (int i = 0; i < 4; ++i)
    #pragma unroll
    for (int j = 0; j < 2; ++j)
      acc[i][j] = (f32x4){0.f,0.f,0.f,0.f};

  for (int k0 = kStart; k0 < kEnd; k0 += 64) {
    #pragma unroll
    for (int r = 0; r < 2; ++r) { GLD16(aP[r], aL[r]); aP[r] += 64; }
    #pragma unroll
    for (int r = 0; r < 2; ++r) { GLD16(bP[r], bL[r]); bP[r] += 64; }
    __syncthreads();
    #pragma unroll
    for (int ks = 0; ks < 2; ++ks) {
      bf16x8 af[4], bfr[2];
      #pragma unroll
      for (int i = 0; i < 4; ++i) {
        const int row = wr*64 + i*16 + col;
        af[i] = *(bf16x8*)&Alds[row*64 + (((ks*4 + quad) ^ (row & 7)) << 3)];
      }
      #pragma unroll
      for (int j = 0; j < 2; ++j) {
        const int row = wc*32 + j*16 + col;
        bfr[j] = *(bf16x8*)&Blds[row*64 + (((ks*4 + quad) ^ (row & 7)) << 3)];
      }
      #pragma unroll
      for (int i = 0; i < 4; ++i)
        #pragma unroll
        for (int j = 0; j < 2; ++j)
          acc[i][j] = __builtin_amdgcn_mfma_f32_16x16x32_bf16(af[i], bfr[j], acc[i][j], 0, 0, 0);
    }
    __syncthreads();
  }

  #pragma unroll
  for (int i = 0; i < 4; ++i) {
    const int mBase = m0 + wr*64 + i*16 + quad*4;
    #pragma unroll
    for (int j = 0; j < 2; ++j) {
      const int n = n0 + wc*32 + j*16 + col;
      if (mode == 1) {
        #pragma unroll
        for (int r = 0; r < 4; ++r)
          Cb[(size_t)(mBase+r)*ldc + n] = f2bf(fmaxf(acc[i][j][r], 0.f));
      } else {
        #pragma unroll
        for (int r = 0; r < 4; ++r)
          C[(size_t)(mBase+r)*ldc + n] = acc[i][j][r];
      }
    }
  }
}

// ---------- final so3 conv: 8-partial sum + per-l contraction + fp32 store ----------
__global__ __launch_bounds__(512) void so3_final(
    const float* __restrict__ zpart, const float* __restrict__ psi2,
    float* __restrict__ out)
{
  __shared__ float Zs[8*SO3D];
  __shared__ float P2s[8*SO3D];
  const int b = blockIdx.x, tid = threadIdx.x;
  for (int idx = tid; idx < 8*SO3D; idx += 512) {
    const int f = idx / SO3D, i = idx - f*SO3D;
    float s = 0.f;
    #pragma unroll
    for (int p = 0; p < 8; ++p)
      s += zpart[((size_t)p*1024 + (size_t)b*FHID + f)*512 + i];
    Zs[idx] = s;
    P2s[idx] = psi2[idx];
  }
  __syncthreads();
  if (tid < SO3D) {
    const int i = tid;
    int l;
    if (i < 1) l = 0; else if (i < 10) l = 1; else if (i < 35) l = 2;
    else if (i < 84) l = 3; else if (i < 165) l = 4; else if (i < 286) l = 5; else l = 6;
    const int so = soff(l), d = 2*l+1;
    const int r = i - so;
    const int v = r / d, m = r - v*d;
    float acc = 0.f;
    for (int f = 0; f < 8; ++f)
      for (int u = 0; u < d; ++u)
        acc = fmaf(Zs[f*SO3D + so + u*d + m], P2s[f*SO3D + so + u*d + v], acc);
    const float scale = rsqrtf(8.0f * (float)d);
    out[(size_t)b*SO3D + i] = acc * scale;
  }
}

extern "C" void kernel_launch(void* const* d_in, const int* in_sizes, int n_in,
                              void* d_out, int out_size, void* d_ws, size_t ws_size,
                              hipStream_t stream) {
  const float* fmap    = (const float*)d_in[0];
  const float* conv_w  = (const float*)d_in[1];
  const float* conv_b  = (const float*)d_in[2];
  const float* proj_w  = (const float*)d_in[3];
  const float* proj_Y  = (const float*)d_in[4];
  const float* fs_w    = (const float*)d_in[5];
  const float* fs_Y    = (const float*)d_in[6];
  const float* act_to  = (const float*)d_in[7];
  const float* act_from= (const float*)d_in[8];
  const float* so3_w   = (const float*)d_in[9];
  const float* so3_D   = (const float*)d_in[10];
  float* out           = (float*)d_out;

  // workspace (bytes), lifetime-packed; max ~47.7 MB (< 54.8 MB known-good)
  char* wsb = (char*)d_ws;
  ushort_t* wPT64    = (ushort_t*)(wsb + 0);        // 64x64 bf16 swizzled (8192 B)
  float*    wSumP    = (float*)(wsb + 9728);        // 64 fp32
  float*    wPsi2    = (float*)(wsb + 9984);        // 8x455 fp32 -> 24544, pad 24576
  ushort_t* actToT   = (ushort_t*)(wsb + 24576);    // 4096x512 bf16 -> 4218880
  ushort_t* actFromT = (ushort_t*)(wsb + 4218880);  // 512x4096 bf16 -> 8413184
  ushort_t* yPad     = (ushort_t*)(wsb + 8413184);  // 1024x512 bf16 -> 9461760
  ushort_t* psiT     = (ushort_t*)(wsb + 9461760);  // 512x512 bf16 -> 9986048
  float*    bpsi     = (float*)(wsb + 9986048);     // 512 fp32 -> 9988096
  ushort_t* W2T      = (ushort_t*)(wsb + 9988096);  // 512x2048 bf16 -> 12085248
  ushort_t* xPT      = (ushort_t*)(wsb + 12085248); // 8192x2048 bf16 -> 45639680 (dead after y_blockdiag)
  ushort_t* cwT      = (ushort_t*)(wsb + 45639680); // 2048x512 bf16 -> 47736832 (dead after mid_fused)
  // aliases into dead xPT region:
  ushort_t* gBuf     = (ushort_t*)(wsb + 12085248); // 1024x4096 bf16 -> 20473856
  float*    zPart    = (float*)(wsb + 20473856);    // 8x1024x512 fp32 -> 37251072

  // 1) independent prep: small GEMMs (emit wPT64/psiT directly) + weight transposes + sumP
  prep_all<<<dim3(1354), 256, 0, stream>>>(
      conv_w, proj_w, proj_Y, fs_w, fs_Y, act_to, act_from, so3_w, so3_D,
      wPT64, wSumP, wPsi2, psiT, actToT, actFromT, cwT);
  // 2) fused mid: xPT gemm (2048) + W2T gemm/bpsi (128) + yPad zero-pad (8)
  mid_fused<<<dim3(2184), 256, 0, stream>>>(
      fmap, wPT64, psiT, cwT, conv_b, xPT, W2T, bpsi, yPad);
  // 3) y = block-diag contraction of xPT with W2T + rank-1 bias (BK=128)
  y_blockdiag<<<dim3(164), 256, 0, stream>>>(xPT, W2T, wSumP, bpsi, yPad);
  // 4) g = relu(yPad @ actToT^T) bf16   (M=1024, N=4096, K=512), 8-wave 128^2
  gemm8w_nt<<<dim3(32,8), 512, 0, stream>>>(yPad, actToT, gBuf,
      1024, 4096, 512, 512, 512, 4096, 1, 0);
  // 5) zPart = gBuf @ actFromT^T, split-K=8  (M=1024, N=512, K=4096), 8-wave 128^2
  gemm8w_nt<<<dim3(4,8,8), 512, 0, stream>>>(gBuf, actFromT, zPart,
      1024, 512, 4096, 4096, 4096, 512, 2, 512);
  // 6) final contraction + fp32 store
  so3_final<<<dim3(128), 512, 0, stream>>>(zPart, wPsi2, out);
}